// Round 4
// baseline (752.964 us; speedup 1.0000x reference)
//
#include <hip/hip_runtime.h>
#include <math.h>

#define BB   64      // batch
#define TT   512     // time
#define NCH  7       // channels
#define SS   4       // scales
#define MM   100000  // memory entries
#define DD   64      // embed dim
#define PRED 96      // pred_len
#define NBLK 256     // k2 blocks per scale
#define KPB  391     // ceil(MM/NBLK)

// ---------------- reductions ----------------
__device__ __forceinline__ float wsum(float v){
  v += __shfl_xor(v,32); v += __shfl_xor(v,16); v += __shfl_xor(v,8);
  v += __shfl_xor(v,4);  v += __shfl_xor(v,2);  v += __shfl_xor(v,1);
  return v;
}
__device__ __forceinline__ float wmaxall(float v){
  v = fmaxf(v,__shfl_xor(v,32)); v = fmaxf(v,__shfl_xor(v,16));
  v = fmaxf(v,__shfl_xor(v,8));  v = fmaxf(v,__shfl_xor(v,4));
  v = fmaxf(v,__shfl_xor(v,2));  v = fmaxf(v,__shfl_xor(v,1));
  return v;
}
__device__ __forceinline__ float wminall(float v){
  v = fminf(v,__shfl_xor(v,32)); v = fminf(v,__shfl_xor(v,16));
  v = fminf(v,__shfl_xor(v,8));  v = fminf(v,__shfl_xor(v,4));
  v = fminf(v,__shfl_xor(v,2));  v = fminf(v,__shfl_xor(v,1));
  return v;
}
__device__ __forceinline__ float bsum(float v, float* red, int wid, int lane){
  v = wsum(v);
  __syncthreads();
  if (lane==0) red[wid]=v;
  __syncthreads();
  return (red[0]+red[1])+(red[2]+red[3]);
}
__device__ __forceinline__ float bmax(float v, float* red, int wid, int lane){
  v = wmaxall(v);
  __syncthreads();
  if (lane==0) red[wid]=v;
  __syncthreads();
  return fmaxf(fmaxf(red[0],red[1]),fmaxf(red[2],red[3]));
}
__device__ __forceinline__ float bmin(float v, float* red, int wid, int lane){
  v = wminall(v);
  __syncthreads();
  if (lane==0) red[wid]=v;
  __syncthreads();
  return fminf(fminf(red[0],red[1]),fminf(red[2],red[3]));
}

__device__ __forceinline__ float log_marg(float n, float mean, float var,
                                          float pm, float pv, float nv){
  float post_var = 1.f/(1.f/pv + n/nv);
  float post_mean = post_var*(pm/pv + n*mean/nv);
  return -0.5f*n*logf(6.283185307179586f*nv)
       + 0.5f*logf(post_var/pv)
       - 0.5f*(n*var/nv + mean*mean*n/nv - post_mean*post_mean/post_var + pm*pm/pv);
}

// sorted-desc top5 insert on registers tv0..tv4 / ti0..ti4
#define TOP5_INSERT(v, ii) \
  if ((v) > tv4) { \
    if ((v) > tv0){ tv4=tv3;ti4=ti3;tv3=tv2;ti3=ti2;tv2=tv1;ti2=ti1;tv1=tv0;ti1=ti0;tv0=(v);ti0=(ii);} \
    else if ((v) > tv1){ tv4=tv3;ti4=ti3;tv3=tv2;ti3=ti2;tv2=tv1;ti2=ti1;tv1=(v);ti1=(ii);} \
    else if ((v) > tv2){ tv4=tv3;ti4=ti3;tv3=tv2;ti3=ti2;tv2=(v);ti2=(ii);} \
    else if ((v) > tv3){ tv4=tv3;ti4=ti3;tv3=(v);ti3=(ii);} \
    else { tv4=(v);ti4=(ii);} \
  }

// ---------------- kernel 1: stats + changepoint + mode + encodings ----------------
__global__ __launch_bounds__(256) void k1_setup(
    const float* __restrict__ x,
    const float* __restrict__ cls_w, const float* __restrict__ cls_b,
    const float* __restrict__ prior_mean, const float* __restrict__ prior_var,
    const float* __restrict__ noise_var,
    const float* __restrict__ enc_W, const float* __restrict__ enc_b,
    const float* __restrict__ ln_g, const float* __restrict__ ln_b,
    float* __restrict__ q_ws, int* __restrict__ mode_ws)
{
  __shared__ float xl[TT*NCH];
  __shared__ float xf[TT];
  __shared__ float s1[TT+1];
  __shared__ float s2[TT+1];
  __shared__ float bfl[TT-32];
  __shared__ float xd[TT];
  __shared__ float red[4];
  int b = blockIdx.x, t = threadIdx.x;
  int lane = t & 63, wid = t >> 6;

  for (int i=t; i<TT*NCH; i+=256) xl[i] = x[(size_t)b*TT*NCH + i];
  __syncthreads();
  for (int i=t; i<TT; i+=256){
    float s=0.f;
    #pragma unroll
    for (int n=0;n<NCH;n++) s += xl[i*NCH+n];
    xf[i] = s*(1.0f/NCH);
  }
  __syncthreads();

  // ---- classifier feats (per-channel stats, then mean over channels) ----
  float sum[NCH], ssq[NCH], mxa[NCH], mna[NCH];
  #pragma unroll
  for(int n=0;n<NCH;n++){ sum[n]=0.f; ssq[n]=0.f; mxa[n]=-INFINITY; mna[n]=INFINITY; }
  for (int i=t;i<TT;i+=256){
    #pragma unroll
    for(int n=0;n<NCH;n++){
      float v = xl[i*NCH+n];
      sum[n]+=v; ssq[n]+=v*v; mxa[n]=fmaxf(mxa[n],v); mna[n]=fminf(mna[n],v);
    }
  }
  float f_mean=0.f, f_std=0.f, f_max=0.f, f_min=0.f;
  #pragma unroll
  for(int n=0;n<NCH;n++){
    float sn  = bsum(sum[n], red, wid, lane);
    float qn  = bsum(ssq[n], red, wid, lane);
    float xn  = bmax(mxa[n], red, wid, lane);
    float mn2 = bmin(mna[n], red, wid, lane);
    float m = sn*(1.0f/TT);
    float var = (qn - (float)TT*m*m)*(1.0f/(TT-1));
    f_mean += m; f_std += sqrtf(fmaxf(var, 0.f)); f_max += xn; f_min += mn2;
  }
  f_mean *= (1.0f/NCH); f_std *= (1.0f/NCH); f_max *= (1.0f/NCH); f_min *= (1.0f/NCH);
  f_std = fmaxf(f_std, 1e-6f);
  float trend = 0.f;
  #pragma unroll
  for(int n=0;n<NCH;n++) trend += (xl[(TT-1)*NCH+n]-xl[n]);
  trend *= (1.0f/NCH);
  float z = f_mean*cls_w[0]+f_std*cls_w[1]+f_max*cls_w[2]+f_min*cls_w[3]+trend*cls_w[4]+cls_b[0];
  float extreme_prob = 1.f/(1.f+expf(-z));

  // ---- cumsums (serial, T=512) ----
  if (t==0){
    float a=0.f, c=0.f; s1[0]=0.f; s2[0]=0.f;
    for (int i=0;i<TT;i++){ float v=xf[i]; a+=v; c+=v*v; s1[i+1]=a; s2[i+1]=c; }
  }
  __syncthreads();

  // ---- Bayesian change point ----
  float pm = prior_mean[0];
  float pv = log1pf(expf(prior_var[0]));
  float nv = log1pf(expf(noise_var[0]));
  float sAll = s1[TT], qAll = s2[TT];
  float mw = sAll*(1.0f/TT);
  float vw = fmaxf((qAll - (float)TT*mw*mw)*(1.0f/(TT-1)), 1e-8f);
  float lmw = log_marg((float)TT, mw, vw, pm, pv, nv);
  for (int pp=16+t; pp<TT-16; pp+=256){
    float nl=(float)pp, nr=(float)(TT-pp);
    float ml=s1[pp]/nl;
    float vl=fmaxf((s2[pp]-nl*ml*ml)/(nl-1.f), 1e-8f);
    float sr=sAll-s1[pp], qr=qAll-s2[pp];
    float mr=sr/nr;
    float vr=fmaxf((qr-nr*mr*mr)/(nr-1.f), 1e-8f);
    bfl[pp-16] = log_marg(nl,ml,vl,pm,pv,nv)+log_marg(nr,mr,vr,pm,pv,nv)-lmw;
  }
  __syncthreads();
  float mv = -INFINITY;
  for (int i=t;i<TT-32;i+=256) mv = fmaxf(mv, bfl[i]);
  mv = bmax(mv, red, wid, lane);
  float se=0.f, sme=0.f;
  for (int i=t;i<TT-32;i+=256){
    float e = expf(bfl[i]-mv);
    se += e;
    if (i+16 > 409) sme += e;   // pos > int(512*0.8)=409
  }
  se  = bsum(se,  red, wid, lane);
  sme = bsum(sme, red, wid, lane);
  float near_end = (1.f/(1.f+expf(-mv))) * (sme/se);
  if (t==0) mode_ws[b] = (near_end>0.5f) ? 2 : ((extreme_prob>0.5f) ? 1 : 0);

  // ---- per-scale encodings ----
  for (int si=0; si<SS; si++){
    int ds = 1<<si, Td = TT>>si;
    __syncthreads();
    for (int i=t;i<Td;i+=256)
      xd[i] = (si==0) ? xf[i] : (s1[(i+1)*ds]-s1[i*ds])*(1.0f/(float)ds);
    __syncthreads();
    float s=0.f, qq=0.f, mxv=-INFINITY, mnv=INFINITY;
    for (int i=t;i<Td;i+=256){ float v=xd[i]; s+=v; qq+=v*v; mxv=fmaxf(mxv,v); mnv=fminf(mnv,v); }
    s   = bsum(s,  red, wid, lane);
    qq  = bsum(qq, red, wid, lane);
    mxv = bmax(mxv, red, wid, lane);
    mnv = bmin(mnv, red, wid, lane);
    float m  = s/(float)Td;
    float sd = fmaxf(sqrtf(fmaxf((qq-(float)Td*m*m)/((float)Td-1.f), 0.f)), 1e-6f);
    float tr = xd[Td-1]-xd[0];
    if (t < DD){
      float h = m*enc_W[0*DD+t] + sd*enc_W[1*DD+t] + mxv*enc_W[2*DD+t]
              + mnv*enc_W[3*DD+t] + tr*enc_W[4*DD+t] + enc_b[t];
      float mu  = wsum(h)*(1.0f/DD);
      float dv  = h-mu;
      float var = wsum(dv*dv)*(1.0f/DD);
      float hn  = dv*rsqrtf(var+1e-5f)*ln_g[t] + ln_b[t];
      float nrm2 = wsum(hn*hn);
      q_ws[(((size_t)si*BB)+b)*DD + t] = hn*rsqrtf(nrm2);
    }
  }
}

// ---------------- kernel 2: sims GEMV + per-block top5 ----------------
// Round-1 structure (measured best: lane=key phase A, LDS key tile, sims
// transpose via LDS, phase B lane=batch), with ONE change: the 256
// wave-uniform q ds_read_b128 per tile per wave (the LDS-pipe bottleneck,
// VALUBusy 49%) are replaced by wave-uniform GLOBAL reads -> compiler
// scalarizes to s_load through the scalar/constant cache (a third pipe).
// q_ws is 16 KB, read by all blocks -> sK$-hot. FMA reads: v_fmac a, sQ, vK
// (1 SGPR src, legal). qls LDS buffer deleted: LDS 50.7 -> ~33 KB, 4 blk/CU.
__global__ __launch_bounds__(256,4) void k2_sims(
    const float* __restrict__ keys, const int* __restrict__ labels,
    const float* __restrict__ q_ws, const int* __restrict__ mode_ws,
    float* __restrict__ cand_val, int* __restrict__ cand_idx)
{
  __shared__ float kl[64*64];      // staged key tile (64 keys x 64 dims, linear)
  __shared__ float sims[64*65];    // [key][batch], stride 65
  __shared__ int   lab[64];
  int bid = blockIdx.x;
  int s   = bid / NBLK, blk = bid % NBLK;
  int t = threadIdx.x, lane = t & 63;
  int w = __builtin_amdgcn_readfirstlane(t >> 6);   // wave id, provably uniform
  int k0   = blk*KPB;
  int kend = min(MM, k0+KPB);
  int mode_l = mode_ws[lane];                        // lane = batch in phase B
  const float* qbase = q_ws + (size_t)s*BB*DD;

  float tv0=-INFINITY,tv1=-INFINITY,tv2=-INFINITY,tv3=-INFINITY,tv4=-INFINITY;
  int   ti0=0,ti1=0,ti2=0,ti3=0,ti4=0;

  for (int c0=k0; c0<kend; c0+=64){
    int cn = min(64, kend-c0);
    // stage keys (coalesced float4) + labels
    for (int i=t; i<cn*16; i+=256){
      float4 v = *(const float4*)(keys + (size_t)s*MM*DD + (size_t)c0*DD + (size_t)i*4);
      *(float4*)(kl + i*4) = v;
    }
    if (t < cn) lab[t] = labels[(size_t)s*MM + c0 + t];
    __syncthreads();

    // phase A: lane = key; key row in VGPRs, q via wave-uniform s_load
    if (lane < cn){
      float kr[64];
      #pragma unroll
      for (int kk=0;kk<16;kk++){
        float4 v = *(const float4*)(kl + lane*64 + kk*4);
        kr[kk*4]=v.x; kr[kk*4+1]=v.y; kr[kk*4+2]=v.z; kr[kk*4+3]=v.w;
      }
      int bb0 = w*16;
      #pragma unroll 4
      for (int bi=0; bi<16; bi++){
        const float* qg = qbase + (size_t)(bb0 + bi)*DD;   // wave-uniform -> s_load
        float a0=0.f,a1=0.f,a2=0.f,a3=0.f;
        #pragma unroll
        for (int kk=0;kk<64;kk+=4){
          a0 = fmaf(qg[kk  ], kr[kk  ], a0);
          a1 = fmaf(qg[kk+1], kr[kk+1], a1);
          a2 = fmaf(qg[kk+2], kr[kk+2], a2);
          a3 = fmaf(qg[kk+3], kr[kk+3], a3);
        }
        sims[lane*65 + bb0 + bi] = (a0+a1)+(a2+a3);
      }
    }
    __syncthreads();

    // phase B: lane = batch; each wave scans its 16-key slice
    int mlo = w*16, mhi = min(cn, w*16+16);
    for (int m=mlo; m<mhi; m++){
      int lb = lab[m];
      float v = sims[m*65+lane];
      bool allowed = (mode_l==0) | (lb==mode_l);
      if (allowed){
        int gidx = c0+m;
        TOP5_INSERT(v, gidx)
      }
    }
    __syncthreads();
  }

  // merge 4 wave-lists per batch -> per-block sorted top5
  float* mvp = sims;       // reuse
  int*   mip = (int*)kl;   // reuse
  int slot = (w*64+lane)*5;
  mvp[slot+0]=tv0; mvp[slot+1]=tv1; mvp[slot+2]=tv2; mvp[slot+3]=tv3; mvp[slot+4]=tv4;
  mip[slot+0]=ti0; mip[slot+1]=ti1; mip[slot+2]=ti2; mip[slot+3]=ti3; mip[slot+4]=ti4;
  __syncthreads();
  if (t < 64){
    float tv0=mvp[t*5+0], tv1=mvp[t*5+1], tv2=mvp[t*5+2], tv3=mvp[t*5+3], tv4=mvp[t*5+4];
    int   ti0=mip[t*5+0], ti1=mip[t*5+1], ti2=mip[t*5+2], ti3=mip[t*5+3], ti4=mip[t*5+4];
    #pragma unroll
    for (int ww=1; ww<4; ww++){
      #pragma unroll
      for (int j=0;j<5;j++){
        float v = mvp[(ww*64+t)*5+j]; int ii = mip[(ww*64+t)*5+j];
        TOP5_INSERT(v, ii)
      }
    }
    size_t o = (((size_t)s*NBLK + blk)*BB + t)*5;
    cand_val[o+0]=tv0; cand_val[o+1]=tv1; cand_val[o+2]=tv2; cand_val[o+3]=tv3; cand_val[o+4]=tv4;
    cand_idx[o+0]=ti0; cand_idx[o+1]=ti1; cand_idx[o+2]=ti2; cand_idx[o+3]=ti3; cand_idx[o+4]=ti4;
  }
}

// ---------------- kernel 3: merge candidates, softmax, gather values ----------------
__global__ __launch_bounds__(256) void k3_merge(
    const float* __restrict__ cand_val, const int* __restrict__ cand_idx,
    const float* __restrict__ values, const float* __restrict__ thresholds,
    float* __restrict__ top1_ws, float* __restrict__ retr_ws,
    float* __restrict__ out)
{
  __shared__ float lv[NBLK*5];
  __shared__ int   li[NBLK*5];
  __shared__ float wsm[5];
  __shared__ int   wix[5];
  int bid = blockIdx.x;
  int s = bid >> 6, b = bid & 63;
  int t = threadIdx.x;
  size_t o = (((size_t)s*NBLK + t)*BB + b)*5;
  float tv0=cand_val[o+0], tv1=cand_val[o+1], tv2=cand_val[o+2], tv3=cand_val[o+3], tv4=cand_val[o+4];
  int   ti0=cand_idx[o+0], ti1=cand_idx[o+1], ti2=cand_idx[o+2], ti3=cand_idx[o+3], ti4=cand_idx[o+4];
  lv[t*5+0]=tv0; lv[t*5+1]=tv1; lv[t*5+2]=tv2; lv[t*5+3]=tv3; lv[t*5+4]=tv4;
  li[t*5+0]=ti0; li[t*5+1]=ti1; li[t*5+2]=ti2; li[t*5+3]=ti3; li[t*5+4]=ti4;
  __syncthreads();
  for (int stride=128; stride>=1; stride>>=1){
    if (t < stride){
      int p = t+stride;
      #pragma unroll
      for (int j=0;j<5;j++){
        float v = lv[p*5+j]; int ii = li[p*5+j];
        TOP5_INSERT(v, ii)
      }
      lv[t*5+0]=tv0; lv[t*5+1]=tv1; lv[t*5+2]=tv2; lv[t*5+3]=tv3; lv[t*5+4]=tv4;
      li[t*5+0]=ti0; li[t*5+1]=ti1; li[t*5+2]=ti2; li[t*5+3]=ti3; li[t*5+4]=ti4;
    }
    __syncthreads();
  }
  if (t==0){
    float e1=expf(tv1-tv0), e2=expf(tv2-tv0), e3=expf(tv3-tv0), e4=expf(tv4-tv0);
    float inv = 1.f/(1.f+e1+e2+e3+e4);
    wsm[0]=inv; wsm[1]=e1*inv; wsm[2]=e2*inv; wsm[3]=e3*inv; wsm[4]=e4*inv;
    wix[0]=ti0; wix[1]=ti1; wix[2]=ti2; wix[3]=ti3; wix[4]=ti4;
    top1_ws[s*BB+b] = tv0;
    out[(size_t)BB*PRED*NCH + b*SS + s] = 1.f/(1.f+expf(-(tv0-thresholds[s])));
  }
  __syncthreads();
  if (t < PRED){
    float acc=0.f;
    #pragma unroll
    for (int j=0;j<5;j++)
      acc += wsm[j]*values[((size_t)s*MM + wix[j])*PRED + t];
    retr_ws[((size_t)s*BB + b)*PRED + t] = acc;
  }
}

// ---------------- kernel 4: cross-scale fuse + broadcast over channels ----------------
__global__ __launch_bounds__(128) void k4_fuse(
    const float* __restrict__ top1_ws, const float* __restrict__ retr_ws,
    float* __restrict__ out)
{
  int b = blockIdx.x, t = threadIdx.x;
  float t0=top1_ws[b], t1=top1_ws[BB+b], t2=top1_ws[2*BB+b], t3=top1_ws[3*BB+b];
  float mx = fmaxf(fmaxf(t0,t1),fmaxf(t2,t3));
  float e0=expf(t0-mx), e1=expf(t1-mx), e2=expf(t2-mx), e3=expf(t3-mx);
  float inv = 1.f/(e0+e1+e2+e3);
  if (t < PRED){
    float f = (e0*retr_ws[((size_t)0*BB+b)*PRED+t] + e1*retr_ws[((size_t)1*BB+b)*PRED+t]
             + e2*retr_ws[((size_t)2*BB+b)*PRED+t] + e3*retr_ws[((size_t)3*BB+b)*PRED+t]) * inv;
    size_t base = ((size_t)b*PRED + t)*NCH;
    #pragma unroll
    for (int n=0;n<NCH;n++) out[base+n] = f;
  }
}

extern "C" void kernel_launch(void* const* d_in, const int* in_sizes, int n_in,
                              void* d_out, int out_size, void* d_ws, size_t ws_size,
                              hipStream_t stream)
{
  const float* x          = (const float*)d_in[0];
  const float* keys       = (const float*)d_in[1];
  const float* values     = (const float*)d_in[2];
  const int*   labels     = (const int*)  d_in[3];
  const float* thresholds = (const float*)d_in[4];
  const float* cls_w      = (const float*)d_in[5];
  const float* cls_b      = (const float*)d_in[6];
  const float* prior_mean = (const float*)d_in[7];
  const float* prior_var  = (const float*)d_in[8];
  const float* noise_var  = (const float*)d_in[9];
  const float* enc_W      = (const float*)d_in[10];
  const float* enc_b      = (const float*)d_in[11];
  const float* ln_g       = (const float*)d_in[12];
  const float* ln_b       = (const float*)d_in[13];
  float* out = (float*)d_out;

  float* q_ws     = (float*)d_ws;                                   // S*B*D
  int*   mode_ws  = (int*)(q_ws + (size_t)SS*BB*DD);                // B
  float* cand_val = (float*)(mode_ws + BB);                         // S*NBLK*B*5
  int*   cand_idx = (int*)(cand_val + (size_t)SS*NBLK*BB*5);        // S*NBLK*B*5
  float* top1_ws  = (float*)(cand_idx + (size_t)SS*NBLK*BB*5);      // S*B
  float* retr_ws  = top1_ws + SS*BB;                                // S*B*PRED

  k1_setup<<<dim3(BB), dim3(256), 0, stream>>>(x, cls_w, cls_b, prior_mean,
      prior_var, noise_var, enc_W, enc_b, ln_g, ln_b, q_ws, mode_ws);
  k2_sims<<<dim3(SS*NBLK), dim3(256), 0, stream>>>(keys, labels, q_ws, mode_ws,
      cand_val, cand_idx);
  k3_merge<<<dim3(SS*BB), dim3(256), 0, stream>>>(cand_val, cand_idx, values,
      thresholds, top1_ws, retr_ws, out);
  k4_fuse<<<dim3(BB), dim3(128), 0, stream>>>(top1_ws, retr_ws, out);
}

// Round 5
// 224.065 us; speedup vs baseline: 3.3605x; 3.3605x over previous
//
#include <hip/hip_runtime.h>
#include <math.h>

#define BB   64      // batch
#define TT   512     // time
#define NCH  7       // channels
#define SS   4       // scales
#define MM   100000  // memory entries
#define DD   64      // embed dim
#define PRED 96      // pred_len
#define NBLK 256     // k2 blocks per scale
#define KPB  391     // ceil(MM/NBLK)
#define KLS  68      // key LDS row stride (floats): proven conflict-free (round 1)

// ---------------- reductions ----------------
__device__ __forceinline__ float wsum(float v){
  v += __shfl_xor(v,32); v += __shfl_xor(v,16); v += __shfl_xor(v,8);
  v += __shfl_xor(v,4);  v += __shfl_xor(v,2);  v += __shfl_xor(v,1);
  return v;
}
__device__ __forceinline__ float wmaxall(float v){
  v = fmaxf(v,__shfl_xor(v,32)); v = fmaxf(v,__shfl_xor(v,16));
  v = fmaxf(v,__shfl_xor(v,8));  v = fmaxf(v,__shfl_xor(v,4));
  v = fmaxf(v,__shfl_xor(v,2));  v = fmaxf(v,__shfl_xor(v,1));
  return v;
}
__device__ __forceinline__ float wminall(float v){
  v = fminf(v,__shfl_xor(v,32)); v = fminf(v,__shfl_xor(v,16));
  v = fminf(v,__shfl_xor(v,8));  v = fminf(v,__shfl_xor(v,4));
  v = fminf(v,__shfl_xor(v,2));  v = fminf(v,__shfl_xor(v,1));
  return v;
}
__device__ __forceinline__ float bsum(float v, float* red, int wid, int lane){
  v = wsum(v);
  __syncthreads();
  if (lane==0) red[wid]=v;
  __syncthreads();
  return (red[0]+red[1])+(red[2]+red[3]);
}
__device__ __forceinline__ float bmax(float v, float* red, int wid, int lane){
  v = wmaxall(v);
  __syncthreads();
  if (lane==0) red[wid]=v;
  __syncthreads();
  return fmaxf(fmaxf(red[0],red[1]),fmaxf(red[2],red[3]));
}
__device__ __forceinline__ float bmin(float v, float* red, int wid, int lane){
  v = wminall(v);
  __syncthreads();
  if (lane==0) red[wid]=v;
  __syncthreads();
  return fminf(fminf(red[0],red[1]),fminf(red[2],red[3]));
}

__device__ __forceinline__ float log_marg(float n, float mean, float var,
                                          float pm, float pv, float nv){
  float post_var = 1.f/(1.f/pv + n/nv);
  float post_mean = post_var*(pm/pv + n*mean/nv);
  return -0.5f*n*logf(6.283185307179586f*nv)
       + 0.5f*logf(post_var/pv)
       - 0.5f*(n*var/nv + mean*mean*n/nv - post_mean*post_mean/post_var + pm*pm/pv);
}

// sorted-desc top5 insert on registers tv0..tv4 / ti0..ti4
#define TOP5_INSERT(v, ii) \
  if ((v) > tv4) { \
    if ((v) > tv0){ tv4=tv3;ti4=ti3;tv3=tv2;ti3=ti2;tv2=tv1;ti2=ti1;tv1=tv0;ti1=ti0;tv0=(v);ti0=(ii);} \
    else if ((v) > tv1){ tv4=tv3;ti4=ti3;tv3=tv2;ti3=ti2;tv2=tv1;ti2=ti1;tv1=(v);ti1=(ii);} \
    else if ((v) > tv2){ tv4=tv3;ti4=ti3;tv3=tv2;ti3=ti2;tv2=(v);ti2=(ii);} \
    else if ((v) > tv3){ tv4=tv3;ti4=ti3;tv3=(v);ti3=(ii);} \
    else { tv4=(v);ti4=(ii);} \
  }

// ---------------- kernel 1: stats + changepoint + mode + encodings ----------------
__global__ __launch_bounds__(256) void k1_setup(
    const float* __restrict__ x,
    const float* __restrict__ cls_w, const float* __restrict__ cls_b,
    const float* __restrict__ prior_mean, const float* __restrict__ prior_var,
    const float* __restrict__ noise_var,
    const float* __restrict__ enc_W, const float* __restrict__ enc_b,
    const float* __restrict__ ln_g, const float* __restrict__ ln_b,
    float* __restrict__ q_ws, int* __restrict__ mode_ws)
{
  __shared__ float xl[TT*NCH];
  __shared__ float xf[TT];
  __shared__ float s1[TT+1];
  __shared__ float s2[TT+1];
  __shared__ float bfl[TT-32];
  __shared__ float xd[TT];
  __shared__ float red[4];
  int b = blockIdx.x, t = threadIdx.x;
  int lane = t & 63, wid = t >> 6;

  for (int i=t; i<TT*NCH; i+=256) xl[i] = x[(size_t)b*TT*NCH + i];
  __syncthreads();
  for (int i=t; i<TT; i+=256){
    float s=0.f;
    #pragma unroll
    for (int n=0;n<NCH;n++) s += xl[i*NCH+n];
    xf[i] = s*(1.0f/NCH);
  }
  __syncthreads();

  // ---- classifier feats (per-channel stats, then mean over channels) ----
  float sum[NCH], ssq[NCH], mxa[NCH], mna[NCH];
  #pragma unroll
  for(int n=0;n<NCH;n++){ sum[n]=0.f; ssq[n]=0.f; mxa[n]=-INFINITY; mna[n]=INFINITY; }
  for (int i=t;i<TT;i+=256){
    #pragma unroll
    for(int n=0;n<NCH;n++){
      float v = xl[i*NCH+n];
      sum[n]+=v; ssq[n]+=v*v; mxa[n]=fmaxf(mxa[n],v); mna[n]=fminf(mna[n],v);
    }
  }
  float f_mean=0.f, f_std=0.f, f_max=0.f, f_min=0.f;
  #pragma unroll
  for(int n=0;n<NCH;n++){
    float sn  = bsum(sum[n], red, wid, lane);
    float qn  = bsum(ssq[n], red, wid, lane);
    float xn  = bmax(mxa[n], red, wid, lane);
    float mn2 = bmin(mna[n], red, wid, lane);
    float m = sn*(1.0f/TT);
    float var = (qn - (float)TT*m*m)*(1.0f/(TT-1));
    f_mean += m; f_std += sqrtf(fmaxf(var, 0.f)); f_max += xn; f_min += mn2;
  }
  f_mean *= (1.0f/NCH); f_std *= (1.0f/NCH); f_max *= (1.0f/NCH); f_min *= (1.0f/NCH);
  f_std = fmaxf(f_std, 1e-6f);
  float trend = 0.f;
  #pragma unroll
  for(int n=0;n<NCH;n++) trend += (xl[(TT-1)*NCH+n]-xl[n]);
  trend *= (1.0f/NCH);
  float z = f_mean*cls_w[0]+f_std*cls_w[1]+f_max*cls_w[2]+f_min*cls_w[3]+trend*cls_w[4]+cls_b[0];
  float extreme_prob = 1.f/(1.f+expf(-z));

  // ---- cumsums (serial, T=512) ----
  if (t==0){
    float a=0.f, c=0.f; s1[0]=0.f; s2[0]=0.f;
    for (int i=0;i<TT;i++){ float v=xf[i]; a+=v; c+=v*v; s1[i+1]=a; s2[i+1]=c; }
  }
  __syncthreads();

  // ---- Bayesian change point ----
  float pm = prior_mean[0];
  float pv = log1pf(expf(prior_var[0]));
  float nv = log1pf(expf(noise_var[0]));
  float sAll = s1[TT], qAll = s2[TT];
  float mw = sAll*(1.0f/TT);
  float vw = fmaxf((qAll - (float)TT*mw*mw)*(1.0f/(TT-1)), 1e-8f);
  float lmw = log_marg((float)TT, mw, vw, pm, pv, nv);
  for (int pp=16+t; pp<TT-16; pp+=256){
    float nl=(float)pp, nr=(float)(TT-pp);
    float ml=s1[pp]/nl;
    float vl=fmaxf((s2[pp]-nl*ml*ml)/(nl-1.f), 1e-8f);
    float sr=sAll-s1[pp], qr=qAll-s2[pp];
    float mr=sr/nr;
    float vr=fmaxf((qr-nr*mr*mr)/(nr-1.f), 1e-8f);
    bfl[pp-16] = log_marg(nl,ml,vl,pm,pv,nv)+log_marg(nr,mr,vr,pm,pv,nv)-lmw;
  }
  __syncthreads();
  float mv = -INFINITY;
  for (int i=t;i<TT-32;i+=256) mv = fmaxf(mv, bfl[i]);
  mv = bmax(mv, red, wid, lane);
  float se=0.f, sme=0.f;
  for (int i=t;i<TT-32;i+=256){
    float e = expf(bfl[i]-mv);
    se += e;
    if (i+16 > 409) sme += e;   // pos > int(512*0.8)=409
  }
  se  = bsum(se,  red, wid, lane);
  sme = bsum(sme, red, wid, lane);
  float near_end = (1.f/(1.f+expf(-mv))) * (sme/se);
  if (t==0) mode_ws[b] = (near_end>0.5f) ? 2 : ((extreme_prob>0.5f) ? 1 : 0);

  // ---- per-scale encodings ----
  for (int si=0; si<SS; si++){
    int ds = 1<<si, Td = TT>>si;
    __syncthreads();
    for (int i=t;i<Td;i+=256)
      xd[i] = (si==0) ? xf[i] : (s1[(i+1)*ds]-s1[i*ds])*(1.0f/(float)ds);
    __syncthreads();
    float s=0.f, qq=0.f, mxv=-INFINITY, mnv=INFINITY;
    for (int i=t;i<Td;i+=256){ float v=xd[i]; s+=v; qq+=v*v; mxv=fmaxf(mxv,v); mnv=fminf(mnv,v); }
    s   = bsum(s,  red, wid, lane);
    qq  = bsum(qq, red, wid, lane);
    mxv = bmax(mxv, red, wid, lane);
    mnv = bmin(mnv, red, wid, lane);
    float m  = s/(float)Td;
    float sd = fmaxf(sqrtf(fmaxf((qq-(float)Td*m*m)/((float)Td-1.f), 0.f)), 1e-6f);
    float tr = xd[Td-1]-xd[0];
    if (t < DD){
      float h = m*enc_W[0*DD+t] + sd*enc_W[1*DD+t] + mxv*enc_W[2*DD+t]
              + mnv*enc_W[3*DD+t] + tr*enc_W[4*DD+t] + enc_b[t];
      float mu  = wsum(h)*(1.0f/DD);
      float dv  = h-mu;
      float var = wsum(dv*dv)*(1.0f/DD);
      float hn  = dv*rsqrtf(var+1e-5f)*ln_g[t] + ln_b[t];
      float nrm2 = wsum(hn*hn);
      q_ws[(((size_t)si*BB)+b)*DD + t] = hn*rsqrtf(nrm2);
    }
  }
}

// ---------------- kernel 2: sims GEMV + per-block top5 ----------------
// Round-1 proven structure (acc[16], dc-outer, ka/kb per-chunk from the
// stride-68 LDS key tile, 0 bank conflicts, no kr[64]) with ONE change:
// q is read via wave-uniform GLOBAL loads -> scalar pipe (s_load), so the
// 256 broadcast q ds_reads per wave per tile (round-1's LDS-pipe
// bottleneck) disappear. qls buffer deleted.
// NOTE (round-0/round-4 lesson): never hold kr[64] per lane -> scratch.
__global__ __launch_bounds__(256,4) void k2_sims(
    const float* __restrict__ keys, const int* __restrict__ labels,
    const float* __restrict__ q_ws, const int* __restrict__ mode_ws,
    float* __restrict__ cand_val, int* __restrict__ cand_idx)
{
  __shared__ float kl[64*KLS];     // staged key tile [key][dim], stride 68
  __shared__ float sims[64*65];    // [key][batch], stride 65
  __shared__ int   lab[64];
  int bid = blockIdx.x;
  int s   = bid / NBLK, blk = bid % NBLK;
  int t = threadIdx.x, lane = t & 63;
  int w = __builtin_amdgcn_readfirstlane(t >> 6);   // wave id, provably uniform
  int k0   = blk*KPB;
  int kend = min(MM, k0+KPB);
  int mode_l = mode_ws[lane];                        // lane = batch in phase B
  const float* qbase = q_ws + (size_t)s*BB*DD;

  float tv0=-INFINITY,tv1=-INFINITY,tv2=-INFINITY,tv3=-INFINITY,tv4=-INFINITY;
  int   ti0=0,ti1=0,ti2=0,ti3=0,ti4=0;

  for (int c0=k0; c0<kend; c0+=64){
    int cn = min(64, kend-c0);
    // stage keys (coalesced float4 global read, stride-68 LDS rows) + labels
    for (int i=t; i<cn*16; i+=256){
      float4 v = *(const float4*)(keys + (size_t)s*MM*DD + (size_t)c0*DD + (size_t)i*4);
      int key = i >> 4, dch = i & 15;
      *(float4*)(kl + key*KLS + dch*4) = v;
    }
    if (t < cn) lab[t] = labels[(size_t)s*MM + c0 + t];
    __syncthreads();

    // phase A: lane = key; acc[16] over the wave's 16 batches; dc-outer.
    // ka/kb: 2 ds_read_b128 per chunk (conflict-free at stride 68).
    // q: wave-uniform global reads -> s_load through scalar cache.
    if (lane < cn){
      float acc[16];
      #pragma unroll
      for (int bi=0; bi<16; bi++) acc[bi]=0.f;
      const float* kp  = kl + lane*KLS;
      const float* qp0 = qbase + (size_t)(w*16)*DD;
      #pragma unroll 2
      for (int dc=0; dc<DD; dc+=8){
        float4 ka = *(const float4*)(kp + dc);
        float4 kb = *(const float4*)(kp + dc + 4);
        #pragma unroll 2
        for (int bi=0; bi<16; bi++){
          const float* qg = qp0 + bi*DD + dc;      // wave-uniform -> s_load
          acc[bi] += ((ka.x*qg[0] + ka.y*qg[1]) + (ka.z*qg[2] + ka.w*qg[3]))
                   + ((kb.x*qg[4] + kb.y*qg[5]) + (kb.z*qg[6] + kb.w*qg[7]));
        }
      }
      #pragma unroll
      for (int bi=0; bi<16; bi++)
        sims[lane*65 + (w*16+bi)] = acc[bi];
    }
    __syncthreads();

    // phase B: lane = batch; each wave scans its 16-key slice
    int mlo = w*16, mhi = min(cn, w*16+16);
    for (int m=mlo; m<mhi; m++){
      int lb = lab[m];
      float v = sims[m*65+lane];
      bool allowed = (mode_l==0) | (lb==mode_l);
      if (allowed){
        int gidx = c0+m;
        TOP5_INSERT(v, gidx)
      }
    }
    __syncthreads();
  }

  // merge 4 wave-lists per batch -> per-block sorted top5
  float* mvp = sims;       // reuse
  int*   mip = (int*)kl;   // reuse
  int slot = (w*64+lane)*5;
  mvp[slot+0]=tv0; mvp[slot+1]=tv1; mvp[slot+2]=tv2; mvp[slot+3]=tv3; mvp[slot+4]=tv4;
  mip[slot+0]=ti0; mip[slot+1]=ti1; mip[slot+2]=ti2; mip[slot+3]=ti3; mip[slot+4]=ti4;
  __syncthreads();
  if (t < 64){
    float tv0=mvp[t*5+0], tv1=mvp[t*5+1], tv2=mvp[t*5+2], tv3=mvp[t*5+3], tv4=mvp[t*5+4];
    int   ti0=mip[t*5+0], ti1=mip[t*5+1], ti2=mip[t*5+2], ti3=mip[t*5+3], ti4=mip[t*5+4];
    #pragma unroll
    for (int ww=1; ww<4; ww++){
      #pragma unroll
      for (int j=0;j<5;j++){
        float v = mvp[(ww*64+t)*5+j]; int ii = mip[(ww*64+t)*5+j];
        TOP5_INSERT(v, ii)
      }
    }
    size_t o = (((size_t)s*NBLK + blk)*BB + t)*5;
    cand_val[o+0]=tv0; cand_val[o+1]=tv1; cand_val[o+2]=tv2; cand_val[o+3]=tv3; cand_val[o+4]=tv4;
    cand_idx[o+0]=ti0; cand_idx[o+1]=ti1; cand_idx[o+2]=ti2; cand_idx[o+3]=ti3; cand_idx[o+4]=ti4;
  }
}

// ---------------- kernel 3: merge candidates, softmax, gather values ----------------
__global__ __launch_bounds__(256) void k3_merge(
    const float* __restrict__ cand_val, const int* __restrict__ cand_idx,
    const float* __restrict__ values, const float* __restrict__ thresholds,
    float* __restrict__ top1_ws, float* __restrict__ retr_ws,
    float* __restrict__ out)
{
  __shared__ float lv[NBLK*5];
  __shared__ int   li[NBLK*5];
  __shared__ float wsm[5];
  __shared__ int   wix[5];
  int bid = blockIdx.x;
  int s = bid >> 6, b = bid & 63;
  int t = threadIdx.x;
  size_t o = (((size_t)s*NBLK + t)*BB + b)*5;
  float tv0=cand_val[o+0], tv1=cand_val[o+1], tv2=cand_val[o+2], tv3=cand_val[o+3], tv4=cand_val[o+4];
  int   ti0=cand_idx[o+0], ti1=cand_idx[o+1], ti2=cand_idx[o+2], ti3=cand_idx[o+3], ti4=cand_idx[o+4];
  lv[t*5+0]=tv0; lv[t*5+1]=tv1; lv[t*5+2]=tv2; lv[t*5+3]=tv3; lv[t*5+4]=tv4;
  li[t*5+0]=ti0; li[t*5+1]=ti1; li[t*5+2]=ti2; li[t*5+3]=ti3; li[t*5+4]=ti4;
  __syncthreads();
  for (int stride=128; stride>=1; stride>>=1){
    if (t < stride){
      int p = t+stride;
      #pragma unroll
      for (int j=0;j<5;j++){
        float v = lv[p*5+j]; int ii = li[p*5+j];
        TOP5_INSERT(v, ii)
      }
      lv[t*5+0]=tv0; lv[t*5+1]=tv1; lv[t*5+2]=tv2; lv[t*5+3]=tv3; lv[t*5+4]=tv4;
      li[t*5+0]=ti0; li[t*5+1]=ti1; li[t*5+2]=ti2; li[t*5+3]=ti3; li[t*5+4]=ti4;
    }
    __syncthreads();
  }
  if (t==0){
    float e1=expf(tv1-tv0), e2=expf(tv2-tv0), e3=expf(tv3-tv0), e4=expf(tv4-tv0);
    float inv = 1.f/(1.f+e1+e2+e3+e4);
    wsm[0]=inv; wsm[1]=e1*inv; wsm[2]=e2*inv; wsm[3]=e3*inv; wsm[4]=e4*inv;
    wix[0]=ti0; wix[1]=ti1; wix[2]=ti2; wix[3]=ti3; wix[4]=ti4;
    top1_ws[s*BB+b] = tv0;
    out[(size_t)BB*PRED*NCH + b*SS + s] = 1.f/(1.f+expf(-(tv0-thresholds[s])));
  }
  __syncthreads();
  if (t < PRED){
    float acc=0.f;
    #pragma unroll
    for (int j=0;j<5;j++)
      acc += wsm[j]*values[((size_t)s*MM + wix[j])*PRED + t];
    retr_ws[((size_t)s*BB + b)*PRED + t] = acc;
  }
}

// ---------------- kernel 4: cross-scale fuse + broadcast over channels ----------------
__global__ __launch_bounds__(128) void k4_fuse(
    const float* __restrict__ top1_ws, const float* __restrict__ retr_ws,
    float* __restrict__ out)
{
  int b = blockIdx.x, t = threadIdx.x;
  float t0=top1_ws[b], t1=top1_ws[BB+b], t2=top1_ws[2*BB+b], t3=top1_ws[3*BB+b];
  float mx = fmaxf(fmaxf(t0,t1),fmaxf(t2,t3));
  float e0=expf(t0-mx), e1=expf(t1-mx), e2=expf(t2-mx), e3=expf(t3-mx);
  float inv = 1.f/(e0+e1+e2+e3);
  if (t < PRED){
    float f = (e0*retr_ws[((size_t)0*BB+b)*PRED+t] + e1*retr_ws[((size_t)1*BB+b)*PRED+t]
             + e2*retr_ws[((size_t)2*BB+b)*PRED+t] + e3*retr_ws[((size_t)3*BB+b)*PRED+t]) * inv;
    size_t base = ((size_t)b*PRED + t)*NCH;
    #pragma unroll
    for (int n=0;n<NCH;n++) out[base+n] = f;
  }
}

extern "C" void kernel_launch(void* const* d_in, const int* in_sizes, int n_in,
                              void* d_out, int out_size, void* d_ws, size_t ws_size,
                              hipStream_t stream)
{
  const float* x          = (const float*)d_in[0];
  const float* keys       = (const float*)d_in[1];
  const float* values     = (const float*)d_in[2];
  const int*   labels     = (const int*)  d_in[3];
  const float* thresholds = (const float*)d_in[4];
  const float* cls_w      = (const float*)d_in[5];
  const float* cls_b      = (const float*)d_in[6];
  const float* prior_mean = (const float*)d_in[7];
  const float* prior_var  = (const float*)d_in[8];
  const float* noise_var  = (const float*)d_in[9];
  const float* enc_W      = (const float*)d_in[10];
  const float* enc_b      = (const float*)d_in[11];
  const float* ln_g       = (const float*)d_in[12];
  const float* ln_b       = (const float*)d_in[13];
  float* out = (float*)d_out;

  float* q_ws     = (float*)d_ws;                                   // S*B*D
  int*   mode_ws  = (int*)(q_ws + (size_t)SS*BB*DD);                // B
  float* cand_val = (float*)(mode_ws + BB);                         // S*NBLK*B*5
  int*   cand_idx = (int*)(cand_val + (size_t)SS*NBLK*BB*5);        // S*NBLK*B*5
  float* top1_ws  = (float*)(cand_idx + (size_t)SS*NBLK*BB*5);      // S*B
  float* retr_ws  = top1_ws + SS*BB;                                // S*B*PRED

  k1_setup<<<dim3(BB), dim3(256), 0, stream>>>(x, cls_w, cls_b, prior_mean,
      prior_var, noise_var, enc_W, enc_b, ln_g, ln_b, q_ws, mode_ws);
  k2_sims<<<dim3(SS*NBLK), dim3(256), 0, stream>>>(keys, labels, q_ws, mode_ws,
      cand_val, cand_idx);
  k3_merge<<<dim3(SS*BB), dim3(256), 0, stream>>>(cand_val, cand_idx, values,
      thresholds, top1_ws, retr_ws, out);
  k4_fuse<<<dim3(BB), dim3(128), 0, stream>>>(top1_ws, retr_ws, out);
}

// Round 6
// 212.549 us; speedup vs baseline: 3.5426x; 1.0542x over previous
//
#include <hip/hip_runtime.h>
#include <math.h>

#define BB   64      // batch
#define TT   512     // time
#define NCH  7       // channels
#define SS   4       // scales
#define MM   100000  // memory entries
#define DD   64      // embed dim
#define PRED 96      // pred_len
#define NBLK 256     // k2 blocks per scale
#define KPB  391     // ceil(MM/NBLK)
#define KLS  68      // key LDS row stride (floats): proven conflict-free (round 1)

// ---------------- reductions ----------------
__device__ __forceinline__ float wsum(float v){
  v += __shfl_xor(v,32); v += __shfl_xor(v,16); v += __shfl_xor(v,8);
  v += __shfl_xor(v,4);  v += __shfl_xor(v,2);  v += __shfl_xor(v,1);
  return v;
}
__device__ __forceinline__ float wmaxall(float v){
  v = fmaxf(v,__shfl_xor(v,32)); v = fmaxf(v,__shfl_xor(v,16));
  v = fmaxf(v,__shfl_xor(v,8));  v = fmaxf(v,__shfl_xor(v,4));
  v = fmaxf(v,__shfl_xor(v,2));  v = fmaxf(v,__shfl_xor(v,1));
  return v;
}
__device__ __forceinline__ float wminall(float v){
  v = fminf(v,__shfl_xor(v,32)); v = fminf(v,__shfl_xor(v,16));
  v = fminf(v,__shfl_xor(v,8));  v = fminf(v,__shfl_xor(v,4));
  v = fminf(v,__shfl_xor(v,2));  v = fminf(v,__shfl_xor(v,1));
  return v;
}
__device__ __forceinline__ float bsum(float v, float* red, int wid, int lane){
  v = wsum(v);
  __syncthreads();
  if (lane==0) red[wid]=v;
  __syncthreads();
  return (red[0]+red[1])+(red[2]+red[3]);
}
__device__ __forceinline__ float bmax(float v, float* red, int wid, int lane){
  v = wmaxall(v);
  __syncthreads();
  if (lane==0) red[wid]=v;
  __syncthreads();
  return fmaxf(fmaxf(red[0],red[1]),fmaxf(red[2],red[3]));
}
__device__ __forceinline__ float bmin(float v, float* red, int wid, int lane){
  v = wminall(v);
  __syncthreads();
  if (lane==0) red[wid]=v;
  __syncthreads();
  return fminf(fminf(red[0],red[1]),fminf(red[2],red[3]));
}

__device__ __forceinline__ float log_marg(float n, float mean, float var,
                                          float pm, float pv, float nv){
  float post_var = 1.f/(1.f/pv + n/nv);
  float post_mean = post_var*(pm/pv + n*mean/nv);
  return -0.5f*n*logf(6.283185307179586f*nv)
       + 0.5f*logf(post_var/pv)
       - 0.5f*(n*var/nv + mean*mean*n/nv - post_mean*post_mean/post_var + pm*pm/pv);
}

// sorted-desc top5 insert on registers tv0..tv4 / ti0..ti4
#define TOP5_INSERT(v, ii) \
  if ((v) > tv4) { \
    if ((v) > tv0){ tv4=tv3;ti4=ti3;tv3=tv2;ti3=ti2;tv2=tv1;ti2=ti1;tv1=tv0;ti1=ti0;tv0=(v);ti0=(ii);} \
    else if ((v) > tv1){ tv4=tv3;ti4=ti3;tv3=tv2;ti3=ti2;tv2=tv1;ti2=ti1;tv1=(v);ti1=(ii);} \
    else if ((v) > tv2){ tv4=tv3;ti4=ti3;tv3=tv2;ti3=ti2;tv2=(v);ti2=(ii);} \
    else if ((v) > tv3){ tv4=tv3;ti4=ti3;tv3=(v);ti3=(ii);} \
    else { tv4=(v);ti4=(ii);} \
  }

// ---------------- kernel 1: stats + changepoint + mode + encodings ----------------
__global__ __launch_bounds__(256) void k1_setup(
    const float* __restrict__ x,
    const float* __restrict__ cls_w, const float* __restrict__ cls_b,
    const float* __restrict__ prior_mean, const float* __restrict__ prior_var,
    const float* __restrict__ noise_var,
    const float* __restrict__ enc_W, const float* __restrict__ enc_b,
    const float* __restrict__ ln_g, const float* __restrict__ ln_b,
    float* __restrict__ q_ws, int* __restrict__ mode_ws)
{
  __shared__ float xl[TT*NCH];
  __shared__ float xf[TT];
  __shared__ float s1[TT+1];
  __shared__ float s2[TT+1];
  __shared__ float bfl[TT-32];
  __shared__ float xd[TT];
  __shared__ float red[4];
  int b = blockIdx.x, t = threadIdx.x;
  int lane = t & 63, wid = t >> 6;

  for (int i=t; i<TT*NCH; i+=256) xl[i] = x[(size_t)b*TT*NCH + i];
  __syncthreads();
  for (int i=t; i<TT; i+=256){
    float s=0.f;
    #pragma unroll
    for (int n=0;n<NCH;n++) s += xl[i*NCH+n];
    xf[i] = s*(1.0f/NCH);
  }
  __syncthreads();

  // ---- classifier feats (per-channel stats, then mean over channels) ----
  float sum[NCH], ssq[NCH], mxa[NCH], mna[NCH];
  #pragma unroll
  for(int n=0;n<NCH;n++){ sum[n]=0.f; ssq[n]=0.f; mxa[n]=-INFINITY; mna[n]=INFINITY; }
  for (int i=t;i<TT;i+=256){
    #pragma unroll
    for(int n=0;n<NCH;n++){
      float v = xl[i*NCH+n];
      sum[n]+=v; ssq[n]+=v*v; mxa[n]=fmaxf(mxa[n],v); mna[n]=fminf(mna[n],v);
    }
  }
  float f_mean=0.f, f_std=0.f, f_max=0.f, f_min=0.f;
  #pragma unroll
  for(int n=0;n<NCH;n++){
    float sn  = bsum(sum[n], red, wid, lane);
    float qn  = bsum(ssq[n], red, wid, lane);
    float xn  = bmax(mxa[n], red, wid, lane);
    float mn2 = bmin(mna[n], red, wid, lane);
    float m = sn*(1.0f/TT);
    float var = (qn - (float)TT*m*m)*(1.0f/(TT-1));
    f_mean += m; f_std += sqrtf(fmaxf(var, 0.f)); f_max += xn; f_min += mn2;
  }
  f_mean *= (1.0f/NCH); f_std *= (1.0f/NCH); f_max *= (1.0f/NCH); f_min *= (1.0f/NCH);
  f_std = fmaxf(f_std, 1e-6f);
  float trend = 0.f;
  #pragma unroll
  for(int n=0;n<NCH;n++) trend += (xl[(TT-1)*NCH+n]-xl[n]);
  trend *= (1.0f/NCH);
  float z = f_mean*cls_w[0]+f_std*cls_w[1]+f_max*cls_w[2]+f_min*cls_w[3]+trend*cls_w[4]+cls_b[0];
  float extreme_prob = 1.f/(1.f+expf(-z));

  // ---- cumsums (serial, T=512) ----
  if (t==0){
    float a=0.f, c=0.f; s1[0]=0.f; s2[0]=0.f;
    for (int i=0;i<TT;i++){ float v=xf[i]; a+=v; c+=v*v; s1[i+1]=a; s2[i+1]=c; }
  }
  __syncthreads();

  // ---- Bayesian change point ----
  float pm = prior_mean[0];
  float pv = log1pf(expf(prior_var[0]));
  float nv = log1pf(expf(noise_var[0]));
  float sAll = s1[TT], qAll = s2[TT];
  float mw = sAll*(1.0f/TT);
  float vw = fmaxf((qAll - (float)TT*mw*mw)*(1.0f/(TT-1)), 1e-8f);
  float lmw = log_marg((float)TT, mw, vw, pm, pv, nv);
  for (int pp=16+t; pp<TT-16; pp+=256){
    float nl=(float)pp, nr=(float)(TT-pp);
    float ml=s1[pp]/nl;
    float vl=fmaxf((s2[pp]-nl*ml*ml)/(nl-1.f), 1e-8f);
    float sr=sAll-s1[pp], qr=qAll-s2[pp];
    float mr=sr/nr;
    float vr=fmaxf((qr-nr*mr*mr)/(nr-1.f), 1e-8f);
    bfl[pp-16] = log_marg(nl,ml,vl,pm,pv,nv)+log_marg(nr,mr,vr,pm,pv,nv)-lmw;
  }
  __syncthreads();
  float mv = -INFINITY;
  for (int i=t;i<TT-32;i+=256) mv = fmaxf(mv, bfl[i]);
  mv = bmax(mv, red, wid, lane);
  float se=0.f, sme=0.f;
  for (int i=t;i<TT-32;i+=256){
    float e = expf(bfl[i]-mv);
    se += e;
    if (i+16 > 409) sme += e;   // pos > int(512*0.8)=409
  }
  se  = bsum(se,  red, wid, lane);
  sme = bsum(sme, red, wid, lane);
  float near_end = (1.f/(1.f+expf(-mv))) * (sme/se);
  if (t==0) mode_ws[b] = (near_end>0.5f) ? 2 : ((extreme_prob>0.5f) ? 1 : 0);

  // ---- per-scale encodings ----
  for (int si=0; si<SS; si++){
    int ds = 1<<si, Td = TT>>si;
    __syncthreads();
    for (int i=t;i<Td;i+=256)
      xd[i] = (si==0) ? xf[i] : (s1[(i+1)*ds]-s1[i*ds])*(1.0f/(float)ds);
    __syncthreads();
    float s=0.f, qq=0.f, mxv=-INFINITY, mnv=INFINITY;
    for (int i=t;i<Td;i+=256){ float v=xd[i]; s+=v; qq+=v*v; mxv=fmaxf(mxv,v); mnv=fminf(mnv,v); }
    s   = bsum(s,  red, wid, lane);
    qq  = bsum(qq, red, wid, lane);
    mxv = bmax(mxv, red, wid, lane);
    mnv = bmin(mnv, red, wid, lane);
    float m  = s/(float)Td;
    float sd = fmaxf(sqrtf(fmaxf((qq-(float)Td*m*m)/((float)Td-1.f), 0.f)), 1e-6f);
    float tr = xd[Td-1]-xd[0];
    if (t < DD){
      float h = m*enc_W[0*DD+t] + sd*enc_W[1*DD+t] + mxv*enc_W[2*DD+t]
              + mnv*enc_W[3*DD+t] + tr*enc_W[4*DD+t] + enc_b[t];
      float mu  = wsum(h)*(1.0f/DD);
      float dv  = h-mu;
      float var = wsum(dv*dv)*(1.0f/DD);
      float hn  = dv*rsqrtf(var+1e-5f)*ln_g[t] + ln_b[t];
      float nrm2 = wsum(hn*hn);
      q_ws[(((size_t)si*BB)+b)*DD + t] = hn*rsqrtf(nrm2);
    }
  }
}

// ---------------- kernel 2: sims GEMV + per-block top5 ----------------
// Round-5 skeleton + two changes:
//  (1) 2 key-tiles (128 keys) per phase-A pass: lane owns key `lane` AND
//      key `64+lane`; every wave-uniform q s_load now feeds 16 FMAs (was 8)
//      -> q/SQC traffic per key halves; iterations per block 7 -> 4.
//  (2) pure fmaf chains (8 FMA per 8 dims exactly; 32 independent acc
//      chains for ILP) instead of the mul/add tree (~12 ops per 8 dims).
// sims stays one 64x65 buffer, drained in two phase-B rounds (LDS ~52 KB,
// 3 blocks/CU). acc0[16]+acc1[16]+4 key float4s ~= 64 VGPR, static idx.
__global__ __launch_bounds__(256,3) void k2_sims(
    const float* __restrict__ keys, const int* __restrict__ labels,
    const float* __restrict__ q_ws, const int* __restrict__ mode_ws,
    float* __restrict__ cand_val, int* __restrict__ cand_idx)
{
  __shared__ float kl[128*KLS];    // staged key tile [key][dim], stride 68
  __shared__ float sims[64*65];    // [key][batch], stride 65
  __shared__ int   lab[128];
  int bid = blockIdx.x;
  int s   = bid / NBLK, blk = bid % NBLK;
  int t = threadIdx.x, lane = t & 63;
  int w = __builtin_amdgcn_readfirstlane(t >> 6);   // wave id, provably uniform
  int k0   = blk*KPB;
  int kend = min(MM, k0+KPB);
  int mode_l = mode_ws[lane];                        // lane = batch in phase B
  const float* qbase = q_ws + (size_t)s*BB*DD;

  float tv0=-INFINITY,tv1=-INFINITY,tv2=-INFINITY,tv3=-INFINITY,tv4=-INFINITY;
  int   ti0=0,ti1=0,ti2=0,ti3=0,ti4=0;

  for (int c0=k0; c0<kend; c0+=128){
    int cnTot = min(128, kend-c0);
    // stage up to 128 keys (coalesced float4 global read, stride-68 rows)
    for (int i=t; i<cnTot*16; i+=256){
      float4 v = *(const float4*)(keys + (size_t)s*MM*DD + (size_t)c0*DD + (size_t)i*4);
      int key = i >> 4, dch = i & 15;
      *(float4*)(kl + key*KLS + dch*4) = v;
    }
    if (t < cnTot) lab[t] = labels[(size_t)s*MM + c0 + t];
    __syncthreads();

    // phase A: lane owns keys (lane) and (64+lane); acc over wave's 16 batches.
    // Unguarded: tail lanes compute on stale LDS, results never read.
    float acc0[16], acc1[16];
    #pragma unroll
    for (int bi=0; bi<16; bi++){ acc0[bi]=0.f; acc1[bi]=0.f; }
    const float* kp0 = kl + lane*KLS;
    const float* kp1 = kl + (64+lane)*KLS;
    const float* qp0 = qbase + (size_t)(w*16)*DD;
    #pragma unroll 2
    for (int dc=0; dc<DD; dc+=8){
      float4 ka0 = *(const float4*)(kp0 + dc);
      float4 kb0 = *(const float4*)(kp0 + dc + 4);
      float4 ka1 = *(const float4*)(kp1 + dc);
      float4 kb1 = *(const float4*)(kp1 + dc + 4);
      #pragma unroll 4
      for (int bi=0; bi<16; bi++){
        const float* qg = qp0 + bi*DD + dc;        // wave-uniform -> s_load
        float q0=qg[0], q1=qg[1], q2=qg[2], q3=qg[3];
        float q4=qg[4], q5=qg[5], q6=qg[6], q7=qg[7];
        float a0 = acc0[bi], a1 = acc1[bi];
        a0 = fmaf(q0, ka0.x, a0);  a1 = fmaf(q0, ka1.x, a1);
        a0 = fmaf(q1, ka0.y, a0);  a1 = fmaf(q1, ka1.y, a1);
        a0 = fmaf(q2, ka0.z, a0);  a1 = fmaf(q2, ka1.z, a1);
        a0 = fmaf(q3, ka0.w, a0);  a1 = fmaf(q3, ka1.w, a1);
        a0 = fmaf(q4, kb0.x, a0);  a1 = fmaf(q4, kb1.x, a1);
        a0 = fmaf(q5, kb0.y, a0);  a1 = fmaf(q5, kb1.y, a1);
        a0 = fmaf(q6, kb0.z, a0);  a1 = fmaf(q6, kb1.z, a1);
        a0 = fmaf(q7, kb0.w, a0);  a1 = fmaf(q7, kb1.w, a1);
        acc0[bi] = a0; acc1[bi] = a1;
      }
    }

    // ---- tile 0: sims write + phase B ----
    #pragma unroll
    for (int bi=0; bi<16; bi++)
      sims[lane*65 + (w*16+bi)] = acc0[bi];
    __syncthreads();
    {
      int cn0 = min(64, cnTot);
      int mlo = w*16, mhi = min(cn0, w*16+16);
      for (int m=mlo; m<mhi; m++){
        int lb = lab[m];
        float v = sims[m*65+lane];
        bool allowed = (mode_l==0) | (lb==mode_l);
        if (allowed){
          int gidx = c0+m;
          TOP5_INSERT(v, gidx)
        }
      }
    }
    __syncthreads();

    // ---- tile 1 (if present): sims write + phase B ----
    if (cnTot > 64){
      #pragma unroll
      for (int bi=0; bi<16; bi++)
        sims[lane*65 + (w*16+bi)] = acc1[bi];
      __syncthreads();
      int cn1 = cnTot - 64;
      int mlo = w*16, mhi = min(cn1, w*16+16);
      for (int m=mlo; m<mhi; m++){
        int lb = lab[64+m];
        float v = sims[m*65+lane];
        bool allowed = (mode_l==0) | (lb==mode_l);
        if (allowed){
          int gidx = c0+64+m;
          TOP5_INSERT(v, gidx)
        }
      }
      __syncthreads();
    }
  }

  // merge 4 wave-lists per batch -> per-block sorted top5
  float* mvp = sims;       // reuse
  int*   mip = (int*)kl;   // reuse
  int slot = (w*64+lane)*5;
  mvp[slot+0]=tv0; mvp[slot+1]=tv1; mvp[slot+2]=tv2; mvp[slot+3]=tv3; mvp[slot+4]=tv4;
  mip[slot+0]=ti0; mip[slot+1]=ti1; mip[slot+2]=ti2; mip[slot+3]=ti3; mip[slot+4]=ti4;
  __syncthreads();
  if (t < 64){
    float tv0=mvp[t*5+0], tv1=mvp[t*5+1], tv2=mvp[t*5+2], tv3=mvp[t*5+3], tv4=mvp[t*5+4];
    int   ti0=mip[t*5+0], ti1=mip[t*5+1], ti2=mip[t*5+2], ti3=mip[t*5+3], ti4=mip[t*5+4];
    #pragma unroll
    for (int ww=1; ww<4; ww++){
      #pragma unroll
      for (int j=0;j<5;j++){
        float v = mvp[(ww*64+t)*5+j]; int ii = mip[(ww*64+t)*5+j];
        TOP5_INSERT(v, ii)
      }
    }
    size_t o = (((size_t)s*NBLK + blk)*BB + t)*5;
    cand_val[o+0]=tv0; cand_val[o+1]=tv1; cand_val[o+2]=tv2; cand_val[o+3]=tv3; cand_val[o+4]=tv4;
    cand_idx[o+0]=ti0; cand_idx[o+1]=ti1; cand_idx[o+2]=ti2; cand_idx[o+3]=ti3; cand_idx[o+4]=ti4;
  }
}

// ---------------- kernel 3: merge candidates, softmax, gather values ----------------
__global__ __launch_bounds__(256) void k3_merge(
    const float* __restrict__ cand_val, const int* __restrict__ cand_idx,
    const float* __restrict__ values, const float* __restrict__ thresholds,
    float* __restrict__ top1_ws, float* __restrict__ retr_ws,
    float* __restrict__ out)
{
  __shared__ float lv[NBLK*5];
  __shared__ int   li[NBLK*5];
  __shared__ float wsm[5];
  __shared__ int   wix[5];
  int bid = blockIdx.x;
  int s = bid >> 6, b = bid & 63;
  int t = threadIdx.x;
  size_t o = (((size_t)s*NBLK + t)*BB + b)*5;
  float tv0=cand_val[o+0], tv1=cand_val[o+1], tv2=cand_val[o+2], tv3=cand_val[o+3], tv4=cand_val[o+4];
  int   ti0=cand_idx[o+0], ti1=cand_idx[o+1], ti2=cand_idx[o+2], ti3=cand_idx[o+3], ti4=cand_idx[o+4];
  lv[t*5+0]=tv0; lv[t*5+1]=tv1; lv[t*5+2]=tv2; lv[t*5+3]=tv3; lv[t*5+4]=tv4;
  li[t*5+0]=ti0; li[t*5+1]=ti1; li[t*5+2]=ti2; li[t*5+3]=ti3; li[t*5+4]=ti4;
  __syncthreads();
  for (int stride=128; stride>=1; stride>>=1){
    if (t < stride){
      int p = t+stride;
      #pragma unroll
      for (int j=0;j<5;j++){
        float v = lv[p*5+j]; int ii = li[p*5+j];
        TOP5_INSERT(v, ii)
      }
      lv[t*5+0]=tv0; lv[t*5+1]=tv1; lv[t*5+2]=tv2; lv[t*5+3]=tv3; lv[t*5+4]=tv4;
      li[t*5+0]=ti0; li[t*5+1]=ti1; li[t*5+2]=ti2; li[t*5+3]=ti3; li[t*5+4]=ti4;
    }
    __syncthreads();
  }
  if (t==0){
    float e1=expf(tv1-tv0), e2=expf(tv2-tv0), e3=expf(tv3-tv0), e4=expf(tv4-tv0);
    float inv = 1.f/(1.f+e1+e2+e3+e4);
    wsm[0]=inv; wsm[1]=e1*inv; wsm[2]=e2*inv; wsm[3]=e3*inv; wsm[4]=e4*inv;
    wix[0]=ti0; wix[1]=ti1; wix[2]=ti2; wix[3]=ti3; wix[4]=ti4;
    top1_ws[s*BB+b] = tv0;
    out[(size_t)BB*PRED*NCH + b*SS + s] = 1.f/(1.f+expf(-(tv0-thresholds[s])));
  }
  __syncthreads();
  if (t < PRED){
    float acc=0.f;
    #pragma unroll
    for (int j=0;j<5;j++)
      acc += wsm[j]*values[((size_t)s*MM + wix[j])*PRED + t];
    retr_ws[((size_t)s*BB + b)*PRED + t] = acc;
  }
}

// ---------------- kernel 4: cross-scale fuse + broadcast over channels ----------------
__global__ __launch_bounds__(128) void k4_fuse(
    const float* __restrict__ top1_ws, const float* __restrict__ retr_ws,
    float* __restrict__ out)
{
  int b = blockIdx.x, t = threadIdx.x;
  float t0=top1_ws[b], t1=top1_ws[BB+b], t2=top1_ws[2*BB+b], t3=top1_ws[3*BB+b];
  float mx = fmaxf(fmaxf(t0,t1),fmaxf(t2,t3));
  float e0=expf(t0-mx), e1=expf(t1-mx), e2=expf(t2-mx), e3=expf(t3-mx);
  float inv = 1.f/(e0+e1+e2+e3);
  if (t < PRED){
    float f = (e0*retr_ws[((size_t)0*BB+b)*PRED+t] + e1*retr_ws[((size_t)1*BB+b)*PRED+t]
             + e2*retr_ws[((size_t)2*BB+b)*PRED+t] + e3*retr_ws[((size_t)3*BB+b)*PRED+t]) * inv;
    size_t base = ((size_t)b*PRED + t)*NCH;
    #pragma unroll
    for (int n=0;n<NCH;n++) out[base+n] = f;
  }
}

extern "C" void kernel_launch(void* const* d_in, const int* in_sizes, int n_in,
                              void* d_out, int out_size, void* d_ws, size_t ws_size,
                              hipStream_t stream)
{
  const float* x          = (const float*)d_in[0];
  const float* keys       = (const float*)d_in[1];
  const float* values     = (const float*)d_in[2];
  const int*   labels     = (const int*)  d_in[3];
  const float* thresholds = (const float*)d_in[4];
  const float* cls_w      = (const float*)d_in[5];
  const float* cls_b      = (const float*)d_in[6];
  const float* prior_mean = (const float*)d_in[7];
  const float* prior_var  = (const float*)d_in[8];
  const float* noise_var  = (const float*)d_in[9];
  const float* enc_W      = (const float*)d_in[10];
  const float* enc_b      = (const float*)d_in[11];
  const float* ln_g       = (const float*)d_in[12];
  const float* ln_b       = (const float*)d_in[13];
  float* out = (float*)d_out;

  float* q_ws     = (float*)d_ws;                                   // S*B*D
  int*   mode_ws  = (int*)(q_ws + (size_t)SS*BB*DD);                // B
  float* cand_val = (float*)(mode_ws + BB);                         // S*NBLK*B*5
  int*   cand_idx = (int*)(cand_val + (size_t)SS*NBLK*BB*5);        // S*NBLK*B*5
  float* top1_ws  = (float*)(cand_idx + (size_t)SS*NBLK*BB*5);      // S*B
  float* retr_ws  = top1_ws + SS*BB;                                // S*B*PRED

  k1_setup<<<dim3(BB), dim3(256), 0, stream>>>(x, cls_w, cls_b, prior_mean,
      prior_var, noise_var, enc_W, enc_b, ln_g, ln_b, q_ws, mode_ws);
  k2_sims<<<dim3(SS*NBLK), dim3(256), 0, stream>>>(keys, labels, q_ws, mode_ws,
      cand_val, cand_idx);
  k3_merge<<<dim3(SS*BB), dim3(256), 0, stream>>>(cand_val, cand_idx, values,
      thresholds, top1_ws, retr_ws, out);
  k4_fuse<<<dim3(BB), dim3(128), 0, stream>>>(top1_ws, retr_ws, out);
}

// Round 7
// 92.040 us; speedup vs baseline: 8.1808x; 2.3093x over previous
//
#include <hip/hip_runtime.h>
#include <math.h>

#define BB   64      // batch
#define TT   512     // time
#define NCH  7       // channels
#define SS   4       // scales
#define MM   100000  // memory entries
#define DD   64      // embed dim
#define PRED 96      // pred_len
#define NBLK 256     // k2 blocks per scale
#define KPB  391     // ceil(MM/NBLK)
#define KLSH 72      // f16 plane row stride (shorts): 144B rows -> 16B-aligned b128 frags

typedef __attribute__((ext_vector_type(8))) _Float16 f16x8;
typedef __attribute__((ext_vector_type(4))) _Float16 f16x4;
typedef __attribute__((ext_vector_type(4))) float    f32x4;

// ---------------- reductions ----------------
__device__ __forceinline__ float wsum(float v){
  v += __shfl_xor(v,32); v += __shfl_xor(v,16); v += __shfl_xor(v,8);
  v += __shfl_xor(v,4);  v += __shfl_xor(v,2);  v += __shfl_xor(v,1);
  return v;
}
__device__ __forceinline__ float wmaxall(float v){
  v = fmaxf(v,__shfl_xor(v,32)); v = fmaxf(v,__shfl_xor(v,16));
  v = fmaxf(v,__shfl_xor(v,8));  v = fmaxf(v,__shfl_xor(v,4));
  v = fmaxf(v,__shfl_xor(v,2));  v = fmaxf(v,__shfl_xor(v,1));
  return v;
}
__device__ __forceinline__ float wminall(float v){
  v = fminf(v,__shfl_xor(v,32)); v = fminf(v,__shfl_xor(v,16));
  v = fminf(v,__shfl_xor(v,8));  v = fminf(v,__shfl_xor(v,4));
  v = fminf(v,__shfl_xor(v,2));  v = fminf(v,__shfl_xor(v,1));
  return v;
}
__device__ __forceinline__ float bsum(float v, float* red, int wid, int lane){
  v = wsum(v);
  __syncthreads();
  if (lane==0) red[wid]=v;
  __syncthreads();
  return (red[0]+red[1])+(red[2]+red[3]);
}
__device__ __forceinline__ float bmax(float v, float* red, int wid, int lane){
  v = wmaxall(v);
  __syncthreads();
  if (lane==0) red[wid]=v;
  __syncthreads();
  return fmaxf(fmaxf(red[0],red[1]),fmaxf(red[2],red[3]));
}
__device__ __forceinline__ float bmin(float v, float* red, int wid, int lane){
  v = wminall(v);
  __syncthreads();
  if (lane==0) red[wid]=v;
  __syncthreads();
  return fminf(fminf(red[0],red[1]),fminf(red[2],red[3]));
}

__device__ __forceinline__ float log_marg(float n, float mean, float var,
                                          float pm, float pv, float nv){
  float post_var = 1.f/(1.f/pv + n/nv);
  float post_mean = post_var*(pm/pv + n*mean/nv);
  return -0.5f*n*logf(6.283185307179586f*nv)
       + 0.5f*logf(post_var/pv)
       - 0.5f*(n*var/nv + mean*mean*n/nv - post_mean*post_mean/post_var + pm*pm/pv);
}

// sorted-desc top5 insert on registers tv0..tv4 / ti0..ti4
#define TOP5_INSERT(v, ii) \
  if ((v) > tv4) { \
    if ((v) > tv0){ tv4=tv3;ti4=ti3;tv3=tv2;ti3=ti2;tv2=tv1;ti2=ti1;tv1=tv0;ti1=ti0;tv0=(v);ti0=(ii);} \
    else if ((v) > tv1){ tv4=tv3;ti4=ti3;tv3=tv2;ti3=ti2;tv2=tv1;ti2=ti1;tv1=(v);ti1=(ii);} \
    else if ((v) > tv2){ tv4=tv3;ti4=ti3;tv3=tv2;ti3=ti2;tv2=(v);ti2=(ii);} \
    else if ((v) > tv3){ tv4=tv3;ti4=ti3;tv3=(v);ti3=(ii);} \
    else { tv4=(v);ti4=(ii);} \
  }

// split one float into fp16 hi/lo pair (hi = RNE(x), lo = RNE(x - hi))
#define SPLITQ(H, L, slot, val) { \
  _Float16 _h = (_Float16)(val); \
  (H)[slot] = _h; \
  (L)[slot] = (_Float16)((val) - (float)_h); }

// ---------------- kernel 1: stats + changepoint + mode + encodings ----------------
__global__ __launch_bounds__(256) void k1_setup(
    const float* __restrict__ x,
    const float* __restrict__ cls_w, const float* __restrict__ cls_b,
    const float* __restrict__ prior_mean, const float* __restrict__ prior_var,
    const float* __restrict__ noise_var,
    const float* __restrict__ enc_W, const float* __restrict__ enc_b,
    const float* __restrict__ ln_g, const float* __restrict__ ln_b,
    float* __restrict__ q_ws, int* __restrict__ mode_ws)
{
  __shared__ float xl[TT*NCH];
  __shared__ float xf[TT];
  __shared__ float s1[TT+1];
  __shared__ float s2[TT+1];
  __shared__ float bfl[TT-32];
  __shared__ float xd[TT];
  __shared__ float red[4];
  int b = blockIdx.x, t = threadIdx.x;
  int lane = t & 63, wid = t >> 6;

  for (int i=t; i<TT*NCH; i+=256) xl[i] = x[(size_t)b*TT*NCH + i];
  __syncthreads();
  for (int i=t; i<TT; i+=256){
    float s=0.f;
    #pragma unroll
    for (int n=0;n<NCH;n++) s += xl[i*NCH+n];
    xf[i] = s*(1.0f/NCH);
  }
  __syncthreads();

  // ---- classifier feats (per-channel stats, then mean over channels) ----
  float sum[NCH], ssq[NCH], mxa[NCH], mna[NCH];
  #pragma unroll
  for(int n=0;n<NCH;n++){ sum[n]=0.f; ssq[n]=0.f; mxa[n]=-INFINITY; mna[n]=INFINITY; }
  for (int i=t;i<TT;i+=256){
    #pragma unroll
    for(int n=0;n<NCH;n++){
      float v = xl[i*NCH+n];
      sum[n]+=v; ssq[n]+=v*v; mxa[n]=fmaxf(mxa[n],v); mna[n]=fminf(mna[n],v);
    }
  }
  float f_mean=0.f, f_std=0.f, f_max=0.f, f_min=0.f;
  #pragma unroll
  for(int n=0;n<NCH;n++){
    float sn  = bsum(sum[n], red, wid, lane);
    float qn  = bsum(ssq[n], red, wid, lane);
    float xn  = bmax(mxa[n], red, wid, lane);
    float mn2 = bmin(mna[n], red, wid, lane);
    float m = sn*(1.0f/TT);
    float var = (qn - (float)TT*m*m)*(1.0f/(TT-1));
    f_mean += m; f_std += sqrtf(fmaxf(var, 0.f)); f_max += xn; f_min += mn2;
  }
  f_mean *= (1.0f/NCH); f_std *= (1.0f/NCH); f_max *= (1.0f/NCH); f_min *= (1.0f/NCH);
  f_std = fmaxf(f_std, 1e-6f);
  float trend = 0.f;
  #pragma unroll
  for(int n=0;n<NCH;n++) trend += (xl[(TT-1)*NCH+n]-xl[n]);
  trend *= (1.0f/NCH);
  float z = f_mean*cls_w[0]+f_std*cls_w[1]+f_max*cls_w[2]+f_min*cls_w[3]+trend*cls_w[4]+cls_b[0];
  float extreme_prob = 1.f/(1.f+expf(-z));

  // ---- cumsums (serial, T=512) ----
  if (t==0){
    float a=0.f, c=0.f; s1[0]=0.f; s2[0]=0.f;
    for (int i=0;i<TT;i++){ float v=xf[i]; a+=v; c+=v*v; s1[i+1]=a; s2[i+1]=c; }
  }
  __syncthreads();

  // ---- Bayesian change point ----
  float pm = prior_mean[0];
  float pv = log1pf(expf(prior_var[0]));
  float nv = log1pf(expf(noise_var[0]));
  float sAll = s1[TT], qAll = s2[TT];
  float mw = sAll*(1.0f/TT);
  float vw = fmaxf((qAll - (float)TT*mw*mw)*(1.0f/(TT-1)), 1e-8f);
  float lmw = log_marg((float)TT, mw, vw, pm, pv, nv);
  for (int pp=16+t; pp<TT-16; pp+=256){
    float nl=(float)pp, nr=(float)(TT-pp);
    float ml=s1[pp]/nl;
    float vl=fmaxf((s2[pp]-nl*ml*ml)/(nl-1.f), 1e-8f);
    float sr=sAll-s1[pp], qr=qAll-s2[pp];
    float mr=sr/nr;
    float vr=fmaxf((qr-nr*mr*mr)/(nr-1.f), 1e-8f);
    bfl[pp-16] = log_marg(nl,ml,vl,pm,pv,nv)+log_marg(nr,mr,vr,pm,pv,nv)-lmw;
  }
  __syncthreads();
  float mv = -INFINITY;
  for (int i=t;i<TT-32;i+=256) mv = fmaxf(mv, bfl[i]);
  mv = bmax(mv, red, wid, lane);
  float se=0.f, sme=0.f;
  for (int i=t;i<TT-32;i+=256){
    float e = expf(bfl[i]-mv);
    se += e;
    if (i+16 > 409) sme += e;   // pos > int(512*0.8)=409
  }
  se  = bsum(se,  red, wid, lane);
  sme = bsum(sme, red, wid, lane);
  float near_end = (1.f/(1.f+expf(-mv))) * (sme/se);
  if (t==0) mode_ws[b] = (near_end>0.5f) ? 2 : ((extreme_prob>0.5f) ? 1 : 0);

  // ---- per-scale encodings ----
  for (int si=0; si<SS; si++){
    int ds = 1<<si, Td = TT>>si;
    __syncthreads();
    for (int i=t;i<Td;i+=256)
      xd[i] = (si==0) ? xf[i] : (s1[(i+1)*ds]-s1[i*ds])*(1.0f/(float)ds);
    __syncthreads();
    float s=0.f, qq=0.f, mxv=-INFINITY, mnv=INFINITY;
    for (int i=t;i<Td;i+=256){ float v=xd[i]; s+=v; qq+=v*v; mxv=fmaxf(mxv,v); mnv=fminf(mnv,v); }
    s   = bsum(s,  red, wid, lane);
    qq  = bsum(qq, red, wid, lane);
    mxv = bmax(mxv, red, wid, lane);
    mnv = bmin(mnv, red, wid, lane);
    float m  = s/(float)Td;
    float sd = fmaxf(sqrtf(fmaxf((qq-(float)Td*m*m)/((float)Td-1.f), 0.f)), 1e-6f);
    float tr = xd[Td-1]-xd[0];
    if (t < DD){
      float h = m*enc_W[0*DD+t] + sd*enc_W[1*DD+t] + mxv*enc_W[2*DD+t]
              + mnv*enc_W[3*DD+t] + tr*enc_W[4*DD+t] + enc_b[t];
      float mu  = wsum(h)*(1.0f/DD);
      float dv  = h-mu;
      float var = wsum(dv*dv)*(1.0f/DD);
      float hn  = dv*rsqrtf(var+1e-5f)*ln_g[t] + ln_b[t];
      float nrm2 = wsum(hn*hn);
      q_ws[(((size_t)si*BB)+b)*DD + t] = hn*rsqrtf(nrm2);
    }
  }
}

// stage one 64-key tile: fp32 -> fp16 hi/lo planes (split-fp16).
// Row stride KLSH=72 shorts (144B) keeps every 8-half fragment 16B-aligned.
__device__ __forceinline__ void stage_tile(const float* __restrict__ kb, int c0, int cn,
                                           int t, _Float16* khi, _Float16* klo){
  for (int i=t; i<cn*16; i+=256){
    float4 v = *(const float4*)(kb + (size_t)c0*DD + (size_t)i*4);
    int key = i>>4, d0 = (i&15)*4;
    _Float16 h0=(_Float16)v.x, h1=(_Float16)v.y, h2=(_Float16)v.z, h3=(_Float16)v.w;
    _Float16 l0=(_Float16)(v.x-(float)h0), l1=(_Float16)(v.y-(float)h1),
             l2=(_Float16)(v.z-(float)h2), l3=(_Float16)(v.w-(float)h3);
    *(f16x4*)&khi[key*KLSH + d0] = (f16x4){h0,h1,h2,h3};
    *(f16x4*)&klo[key*KLSH + d0] = (f16x4){l0,l1,l2,l3};
  }
}

// ---------------- kernel 2: sims via split-fp16 MFMA + per-block top5 ----------------
// r1/r5/r6 all pinned at 179-195us across VALU mixes -> issue+stall bound.
// Phase A is a [64key x 64batch x K64] GEMM per tile: use mfma_f32_16x16x32_f16
// with split-fp16 (x = hi+lo; A.B ~= hh+hl+lh, residual ~2^-22 -> sims err ~1e-6).
// Per wave per tile: 24 MFMA + 16 ds_read_b128 + 16 sims writes (was ~2000+ VALU).
// q = 4 f16x8 B-frags in REGISTERS, loaded once per block (no 64-reg array).
// Verified layouts (guide m89): D col=lane&15,row=(lane>>4)*4+reg; A/B k=8*(lane>>4)+j.
// stage(t+1) overlaps phase B(t); 2 barriers/tile. LDS 35KB -> 4 blocks/CU.
__global__ __launch_bounds__(256) void k2_sims(
    const float* __restrict__ keys, const int* __restrict__ labels,
    const float* __restrict__ q_ws, const int* __restrict__ mode_ws,
    float* __restrict__ cand_val, int* __restrict__ cand_idx)
{
  __shared__ __align__(16) _Float16 khi[64*KLSH];
  __shared__ __align__(16) _Float16 klo[64*KLSH];
  __shared__ float sims[64*65];    // [key][batch], stride 65 (2-way alias = free)
  int bid = blockIdx.x;
  int s   = bid / NBLK, blk = bid % NBLK;
  int t = threadIdx.x, lane = t & 63;
  int w = __builtin_amdgcn_readfirstlane(t >> 6);   // wave id, provably uniform
  int k0   = blk*KPB;
  int kend = min(MM, k0+KPB);
  int mode_l = mode_ws[lane];                        // lane = batch in phase B
  const float* kb  = keys + (size_t)s*MM*DD;
  const int*   lbb = labels + (size_t)s*MM;

  // ---- B fragments (q, split-fp16) once per block: 16 VGPR total ----
  f16x8 bh0, bl0, bh1, bl1;
  {
    int bb = w*16 + (lane&15);                 // batch (MFMA col)
    int kg = (lane>>4)*8;                      // k-group base
    const float* qg = q_ws + ((size_t)s*BB + bb)*DD + kg;
    float4 qa = *(const float4*)(qg);
    float4 qb = *(const float4*)(qg + 4);
    float4 qc = *(const float4*)(qg + 32);
    float4 qd = *(const float4*)(qg + 36);
    SPLITQ(bh0,bl0,0,qa.x) SPLITQ(bh0,bl0,1,qa.y) SPLITQ(bh0,bl0,2,qa.z) SPLITQ(bh0,bl0,3,qa.w)
    SPLITQ(bh0,bl0,4,qb.x) SPLITQ(bh0,bl0,5,qb.y) SPLITQ(bh0,bl0,6,qb.z) SPLITQ(bh0,bl0,7,qb.w)
    SPLITQ(bh1,bl1,0,qc.x) SPLITQ(bh1,bl1,1,qc.y) SPLITQ(bh1,bl1,2,qc.z) SPLITQ(bh1,bl1,3,qc.w)
    SPLITQ(bh1,bl1,4,qd.x) SPLITQ(bh1,bl1,5,qd.y) SPLITQ(bh1,bl1,6,qd.z) SPLITQ(bh1,bl1,7,qd.w)
  }

  float tv0=-INFINITY,tv1=-INFINITY,tv2=-INFINITY,tv3=-INFINITY,tv4=-INFINITY;
  int   ti0=0,ti1=0,ti2=0,ti3=0,ti4=0;

  int nt = (kend - k0 + 63) >> 6;
  stage_tile(kb, k0, min(64, kend-k0), t, khi, klo);
  __syncthreads();

  for (int ti=0; ti<nt; ++ti){
    int c0 = k0 + (ti<<6);
    int cn = min(64, kend - c0);

    // ---- phase A: split-fp16 MFMA, all 64 lanes (stale tail rows unread) ----
    {
      int arow = lane & 15;                    // A row within 16-key subtile
      int kg   = (lane>>4)*8;                  // A k-group
      int cc   = w*16 + (lane&15);             // D col = batch
      int drow = (lane>>4)*4;                  // D row base within subtile
      #pragma unroll
      for (int st=0; st<4; ++st){
        int rbase = (st*16 + arow)*KLSH;
        f16x8 ah0 = *(const f16x8*)&khi[rbase + kg];
        f16x8 al0 = *(const f16x8*)&klo[rbase + kg];
        f16x8 ah1 = *(const f16x8*)&khi[rbase + kg + 32];
        f16x8 al1 = *(const f16x8*)&klo[rbase + kg + 32];
        f32x4 c = {0.f, 0.f, 0.f, 0.f};
        c = __builtin_amdgcn_mfma_f32_16x16x32_f16(ah0, bh0, c, 0, 0, 0);
        c = __builtin_amdgcn_mfma_f32_16x16x32_f16(al0, bh0, c, 0, 0, 0);
        c = __builtin_amdgcn_mfma_f32_16x16x32_f16(ah0, bl0, c, 0, 0, 0);
        c = __builtin_amdgcn_mfma_f32_16x16x32_f16(ah1, bh1, c, 0, 0, 0);
        c = __builtin_amdgcn_mfma_f32_16x16x32_f16(al1, bh1, c, 0, 0, 0);
        c = __builtin_amdgcn_mfma_f32_16x16x32_f16(ah1, bl1, c, 0, 0, 0);
        int r0 = st*16 + drow;
        sims[(r0+0)*65 + cc] = c[0];
        sims[(r0+1)*65 + cc] = c[1];
        sims[(r0+2)*65 + cc] = c[2];
        sims[(r0+3)*65 + cc] = c[3];
      }
    }
    __syncthreads();                            // sims ready; plane reads done

    // stage next tile (writes planes) overlapped with phase B (reads sims)
    if (ti+1 < nt)
      stage_tile(kb, c0+64, min(64, kend-c0-64), t, khi, klo);

    // ---- phase B: lane = batch; each wave scans its 16-key slice ----
    {
      int mlo = w*16, mhi = min(cn, w*16+16);
      for (int m=mlo; m<mhi; m++){
        int lb = lbb[c0+m];                     // wave-uniform -> s_load
        float v = sims[m*65+lane];
        bool allowed = (mode_l==0) | (lb==mode_l);
        if (allowed){
          int gidx = c0+m;
          TOP5_INSERT(v, gidx)
        }
      }
    }
    __syncthreads();                            // planes(t+1) safe to use
  }

  // merge 4 wave-lists per batch -> per-block sorted top5
  float* mvp = sims;       // reuse
  int*   mip = (int*)khi;  // reuse (9216B >= 5120B)
  int slot = (w*64+lane)*5;
  mvp[slot+0]=tv0; mvp[slot+1]=tv1; mvp[slot+2]=tv2; mvp[slot+3]=tv3; mvp[slot+4]=tv4;
  mip[slot+0]=ti0; mip[slot+1]=ti1; mip[slot+2]=ti2; mip[slot+3]=ti3; mip[slot+4]=ti4;
  __syncthreads();
  if (t < 64){
    float tv0=mvp[t*5+0], tv1=mvp[t*5+1], tv2=mvp[t*5+2], tv3=mvp[t*5+3], tv4=mvp[t*5+4];
    int   ti0=mip[t*5+0], ti1=mip[t*5+1], ti2=mip[t*5+2], ti3=mip[t*5+3], ti4=mip[t*5+4];
    #pragma unroll
    for (int ww=1; ww<4; ww++){
      #pragma unroll
      for (int j=0;j<5;j++){
        float v = mvp[(ww*64+t)*5+j]; int ii = mip[(ww*64+t)*5+j];
        TOP5_INSERT(v, ii)
      }
    }
    size_t o = (((size_t)s*NBLK + blk)*BB + t)*5;
    cand_val[o+0]=tv0; cand_val[o+1]=tv1; cand_val[o+2]=tv2; cand_val[o+3]=tv3; cand_val[o+4]=tv4;
    cand_idx[o+0]=ti0; cand_idx[o+1]=ti1; cand_idx[o+2]=ti2; cand_idx[o+3]=ti3; cand_idx[o+4]=ti4;
  }
}

// ---------------- kernel 3: merge candidates, softmax, gather values ----------------
__global__ __launch_bounds__(256) void k3_merge(
    const float* __restrict__ cand_val, const int* __restrict__ cand_idx,
    const float* __restrict__ values, const float* __restrict__ thresholds,
    float* __restrict__ top1_ws, float* __restrict__ retr_ws,
    float* __restrict__ out)
{
  __shared__ float lv[NBLK*5];
  __shared__ int   li[NBLK*5];
  __shared__ float wsm[5];
  __shared__ int   wix[5];
  int bid = blockIdx.x;
  int s = bid >> 6, b = bid & 63;
  int t = threadIdx.x;
  size_t o = (((size_t)s*NBLK + t)*BB + b)*5;
  float tv0=cand_val[o+0], tv1=cand_val[o+1], tv2=cand_val[o+2], tv3=cand_val[o+3], tv4=cand_val[o+4];
  int   ti0=cand_idx[o+0], ti1=cand_idx[o+1], ti2=cand_idx[o+2], ti3=cand_idx[o+3], ti4=cand_idx[o+4];
  lv[t*5+0]=tv0; lv[t*5+1]=tv1; lv[t*5+2]=tv2; lv[t*5+3]=tv3; lv[t*5+4]=tv4;
  li[t*5+0]=ti0; li[t*5+1]=ti1; li[t*5+2]=ti2; li[t*5+3]=ti3; li[t*5+4]=ti4;
  __syncthreads();
  for (int stride=128; stride>=1; stride>>=1){
    if (t < stride){
      int p = t+stride;
      #pragma unroll
      for (int j=0;j<5;j++){
        float v = lv[p*5+j]; int ii = li[p*5+j];
        TOP5_INSERT(v, ii)
      }
      lv[t*5+0]=tv0; lv[t*5+1]=tv1; lv[t*5+2]=tv2; lv[t*5+3]=tv3; lv[t*5+4]=tv4;
      li[t*5+0]=ti0; li[t*5+1]=ti1; li[t*5+2]=ti2; li[t*5+3]=ti3; li[t*5+4]=ti4;
    }
    __syncthreads();
  }
  if (t==0){
    float e1=expf(tv1-tv0), e2=expf(tv2-tv0), e3=expf(tv3-tv0), e4=expf(tv4-tv0);
    float inv = 1.f/(1.f+e1+e2+e3+e4);
    wsm[0]=inv; wsm[1]=e1*inv; wsm[2]=e2*inv; wsm[3]=e3*inv; wsm[4]=e4*inv;
    wix[0]=ti0; wix[1]=ti1; wix[2]=ti2; wix[3]=ti3; wix[4]=ti4;
    top1_ws[s*BB+b] = tv0;
    out[(size_t)BB*PRED*NCH + b*SS + s] = 1.f/(1.f+expf(-(tv0-thresholds[s])));
  }
  __syncthreads();
  if (t < PRED){
    float acc=0.f;
    #pragma unroll
    for (int j=0;j<5;j++)
      acc += wsm[j]*values[((size_t)s*MM + wix[j])*PRED + t];
    retr_ws[((size_t)s*BB + b)*PRED + t] = acc;
  }
}

// ---------------- kernel 4: cross-scale fuse + broadcast over channels ----------------
__global__ __launch_bounds__(128) void k4_fuse(
    const float* __restrict__ top1_ws, const float* __restrict__ retr_ws,
    float* __restrict__ out)
{
  int b = blockIdx.x, t = threadIdx.x;
  float t0=top1_ws[b], t1=top1_ws[BB+b], t2=top1_ws[2*BB+b], t3=top1_ws[3*BB+b];
  float mx = fmaxf(fmaxf(t0,t1),fmaxf(t2,t3));
  float e0=expf(t0-mx), e1=expf(t1-mx), e2=expf(t2-mx), e3=expf(t3-mx);
  float inv = 1.f/(e0+e1+e2+e3);
  if (t < PRED){
    float f = (e0*retr_ws[((size_t)0*BB+b)*PRED+t] + e1*retr_ws[((size_t)1*BB+b)*PRED+t]
             + e2*retr_ws[((size_t)2*BB+b)*PRED+t] + e3*retr_ws[((size_t)3*BB+b)*PRED+t]) * inv;
    size_t base = ((size_t)b*PRED + t)*NCH;
    #pragma unroll
    for (int n=0;n<NCH;n++) out[base+n] = f;
  }
}

extern "C" void kernel_launch(void* const* d_in, const int* in_sizes, int n_in,
                              void* d_out, int out_size, void* d_ws, size_t ws_size,
                              hipStream_t stream)
{
  const float* x          = (const float*)d_in[0];
  const float* keys       = (const float*)d_in[1];
  const float* values     = (const float*)d_in[2];
  const int*   labels     = (const int*)  d_in[3];
  const float* thresholds = (const float*)d_in[4];
  const float* cls_w      = (const float*)d_in[5];
  const float* cls_b      = (const float*)d_in[6];
  const float* prior_mean = (const float*)d_in[7];
  const float* prior_var  = (const float*)d_in[8];
  const float* noise_var  = (const float*)d_in[9];
  const float* enc_W      = (const float*)d_in[10];
  const float* enc_b      = (const float*)d_in[11];
  const float* ln_g       = (const float*)d_in[12];
  const float* ln_b       = (const float*)d_in[13];
  float* out = (float*)d_out;

  float* q_ws     = (float*)d_ws;                                   // S*B*D
  int*   mode_ws  = (int*)(q_ws + (size_t)SS*BB*DD);                // B
  float* cand_val = (float*)(mode_ws + BB);                         // S*NBLK*B*5
  int*   cand_idx = (int*)(cand_val + (size_t)SS*NBLK*BB*5);        // S*NBLK*B*5
  float* top1_ws  = (float*)(cand_idx + (size_t)SS*NBLK*BB*5);      // S*B
  float* retr_ws  = top1_ws + SS*BB;                                // S*B*PRED

  k1_setup<<<dim3(BB), dim3(256), 0, stream>>>(x, cls_w, cls_b, prior_mean,
      prior_var, noise_var, enc_W, enc_b, ln_g, ln_b, q_ws, mode_ws);
  k2_sims<<<dim3(SS*NBLK), dim3(256), 0, stream>>>(keys, labels, q_ws, mode_ws,
      cand_val, cand_idx);
  k3_merge<<<dim3(SS*BB), dim3(256), 0, stream>>>(cand_val, cand_idx, values,
      thresholds, top1_ws, retr_ws, out);
  k4_fuse<<<dim3(BB), dim3(128), 0, stream>>>(top1_ws, retr_ws, out);
}

// Round 8
// 73.456 us; speedup vs baseline: 10.2505x; 1.2530x over previous
//
#include <hip/hip_runtime.h>
#include <math.h>

#define BB   64      // batch
#define TT   512     // time
#define NCH  7       // channels
#define SS   4       // scales
#define MM   100000  // memory entries
#define DD   64      // embed dim
#define PRED 96      // pred_len
#define NBLK 256     // k2 blocks per scale
#define KPB  391     // ceil(MM/NBLK)
#define KLSH 72      // f16 plane row stride (shorts): 144B rows -> 16B-aligned b128 frags

typedef __attribute__((ext_vector_type(8))) _Float16 f16x8;
typedef __attribute__((ext_vector_type(4))) _Float16 f16x4;
typedef __attribute__((ext_vector_type(4))) float    f32x4;

// ---------------- wave reductions ----------------
__device__ __forceinline__ float wsum(float v){
  v += __shfl_xor(v,32); v += __shfl_xor(v,16); v += __shfl_xor(v,8);
  v += __shfl_xor(v,4);  v += __shfl_xor(v,2);  v += __shfl_xor(v,1);
  return v;
}
__device__ __forceinline__ float wmaxall(float v){
  v = fmaxf(v,__shfl_xor(v,32)); v = fmaxf(v,__shfl_xor(v,16));
  v = fmaxf(v,__shfl_xor(v,8));  v = fmaxf(v,__shfl_xor(v,4));
  v = fmaxf(v,__shfl_xor(v,2));  v = fmaxf(v,__shfl_xor(v,1));
  return v;
}
__device__ __forceinline__ float wminall(float v){
  v = fminf(v,__shfl_xor(v,32)); v = fminf(v,__shfl_xor(v,16));
  v = fminf(v,__shfl_xor(v,8));  v = fminf(v,__shfl_xor(v,4));
  v = fminf(v,__shfl_xor(v,2));  v = fminf(v,__shfl_xor(v,1));
  return v;
}

__device__ __forceinline__ float log_marg(float n, float mean, float var,
                                          float pm, float pv, float nv){
  float post_var = 1.f/(1.f/pv + n/nv);
  float post_mean = post_var*(pm/pv + n*mean/nv);
  return -0.5f*n*logf(6.283185307179586f*nv)
       + 0.5f*logf(post_var/pv)
       - 0.5f*(n*var/nv + mean*mean*n/nv - post_mean*post_mean/post_var + pm*pm/pv);
}

// sorted-desc top5 insert on registers tv0..tv4 / ti0..ti4
#define TOP5_INSERT(v, ii) \
  if ((v) > tv4) { \
    if ((v) > tv0){ tv4=tv3;ti4=ti3;tv3=tv2;ti3=ti2;tv2=tv1;ti2=ti1;tv1=tv0;ti1=ti0;tv0=(v);ti0=(ii);} \
    else if ((v) > tv1){ tv4=tv3;ti4=ti3;tv3=tv2;ti3=ti2;tv2=tv1;ti2=ti1;tv1=(v);ti1=(ii);} \
    else if ((v) > tv2){ tv4=tv3;ti4=ti3;tv3=tv2;ti3=ti2;tv2=(v);ti2=(ii);} \
    else if ((v) > tv3){ tv4=tv3;ti4=ti3;tv3=(v);ti3=(ii);} \
    else { tv4=(v);ti4=(ii);} \
  }

// split one float into fp16 hi/lo pair (hi = RNE(x), lo = RNE(x - hi))
#define SPLITQ(H, L, slot, val) { \
  _Float16 _h = (_Float16)(val); \
  (H)[slot] = _h; \
  (L)[slot] = (_Float16)((val) - (float)_h); }

// ---------------- kernel 1: stats + changepoint + mode + encodings ----------------
// vs r7: serial thread-0 cumsum -> parallel Hillis-Steele scan (2 elem/thread);
// ~90 barrier-pairs of block reductions -> batched wave-reduce + 1 barrier each.
__global__ __launch_bounds__(256) void k1_setup(
    const float* __restrict__ x,
    const float* __restrict__ cls_w, const float* __restrict__ cls_b,
    const float* __restrict__ prior_mean, const float* __restrict__ prior_var,
    const float* __restrict__ noise_var,
    const float* __restrict__ enc_W, const float* __restrict__ enc_b,
    const float* __restrict__ ln_g, const float* __restrict__ ln_b,
    float* __restrict__ q_ws, int* __restrict__ mode_ws)
{
  __shared__ float xl[TT*NCH];
  __shared__ float xf[TT];
  __shared__ float s1[TT+1];
  __shared__ float s2[TT+1];
  __shared__ float bfl[TT-32];
  __shared__ float xd[TT];
  __shared__ float rred[28*4];     // batched reduction scratch [stat][wave]
  int b = blockIdx.x, t = threadIdx.x;
  int lane = t & 63, wid = t >> 6;

  for (int i=t; i<TT*NCH; i+=256) xl[i] = x[(size_t)b*TT*NCH + i];
  __syncthreads();
  for (int i=t; i<TT; i+=256){
    float s=0.f;
    #pragma unroll
    for (int n=0;n<NCH;n++) s += xl[i*NCH+n];
    xf[i] = s*(1.0f/NCH);
  }
  __syncthreads();

  // ---- classifier feats: per-thread accumulate, wave-reduce, ONE barrier ----
  {
    float sum[NCH], ssq[NCH], mxa[NCH], mna[NCH];
    #pragma unroll
    for(int n=0;n<NCH;n++){ sum[n]=0.f; ssq[n]=0.f; mxa[n]=-INFINITY; mna[n]=INFINITY; }
    for (int i=t;i<TT;i+=256){
      #pragma unroll
      for(int n=0;n<NCH;n++){
        float v = xl[i*NCH+n];
        sum[n]+=v; ssq[n]+=v*v; mxa[n]=fmaxf(mxa[n],v); mna[n]=fminf(mna[n],v);
      }
    }
    #pragma unroll
    for(int n=0;n<NCH;n++){
      float sn  = wsum(sum[n]);
      float qn  = wsum(ssq[n]);
      float xn  = wmaxall(mxa[n]);
      float mn2 = wminall(mna[n]);
      if (lane==0){
        rred[(n*4+0)*4+wid]=sn;  rred[(n*4+1)*4+wid]=qn;
        rred[(n*4+2)*4+wid]=xn;  rred[(n*4+3)*4+wid]=mn2;
      }
    }
  }
  __syncthreads();
  float extreme_prob;
  {
    float f_mean=0.f, f_std=0.f, f_max=0.f, f_min=0.f;
    #pragma unroll
    for(int n=0;n<NCH;n++){
      const float* r0 = &rred[(n*4+0)*4];
      const float* r1 = &rred[(n*4+1)*4];
      const float* r2 = &rred[(n*4+2)*4];
      const float* r3 = &rred[(n*4+3)*4];
      float sn  = (r0[0]+r0[1])+(r0[2]+r0[3]);
      float qn  = (r1[0]+r1[1])+(r1[2]+r1[3]);
      float xn  = fmaxf(fmaxf(r2[0],r2[1]),fmaxf(r2[2],r2[3]));
      float mn2 = fminf(fminf(r3[0],r3[1]),fminf(r3[2],r3[3]));
      float m = sn*(1.0f/TT);
      float var = (qn - (float)TT*m*m)*(1.0f/(TT-1));
      f_mean += m; f_std += sqrtf(fmaxf(var, 0.f)); f_max += xn; f_min += mn2;
    }
    f_mean *= (1.0f/NCH); f_std *= (1.0f/NCH); f_max *= (1.0f/NCH); f_min *= (1.0f/NCH);
    f_std = fmaxf(f_std, 1e-6f);
    float trend = 0.f;
    #pragma unroll
    for(int n=0;n<NCH;n++) trend += (xl[(TT-1)*NCH+n]-xl[n]);
    trend *= (1.0f/NCH);
    float z = f_mean*cls_w[0]+f_std*cls_w[1]+f_max*cls_w[2]+f_min*cls_w[3]+trend*cls_w[4]+cls_b[0];
    extreme_prob = 1.f/(1.f+expf(-z));
  }

  // ---- parallel cumsum scan (s1: sum, s2: sumsq), 2 elems/thread ----
  {
    float a0 = xf[2*t], a1 = xf[2*t+1];
    float ps = a0+a1, qs = a0*a0 + a1*a1;
    xd[t] = ps; xd[256+t] = qs;
    __syncthreads();
    #pragma unroll
    for (int off=1; off<256; off<<=1){
      float pv=0.f, qv=0.f;
      if (t>=off){ pv = xd[t-off]; qv = xd[256+t-off]; }
      __syncthreads();
      xd[t] += pv; xd[256+t] += qv;
      __syncthreads();
    }
    float ip = xd[t], iq = xd[256+t];       // inclusive through pair t
    s1[2*t+1] = (ip-ps) + a0;  s2[2*t+1] = (iq-qs) + a0*a0;
    s1[2*t+2] = ip;            s2[2*t+2] = iq;
    if (t==0){ s1[0]=0.f; s2[0]=0.f; }
  }
  __syncthreads();

  // ---- Bayesian change point ----
  float pm = prior_mean[0];
  float pv = log1pf(expf(prior_var[0]));
  float nv = log1pf(expf(noise_var[0]));
  float sAll = s1[TT], qAll = s2[TT];
  float mw = sAll*(1.0f/TT);
  float vw = fmaxf((qAll - (float)TT*mw*mw)*(1.0f/(TT-1)), 1e-8f);
  float lmw = log_marg((float)TT, mw, vw, pm, pv, nv);
  for (int pp=16+t; pp<TT-16; pp+=256){
    float nl=(float)pp, nr=(float)(TT-pp);
    float ml=s1[pp]/nl;
    float vl=fmaxf((s2[pp]-nl*ml*ml)/(nl-1.f), 1e-8f);
    float sr=sAll-s1[pp], qr=qAll-s2[pp];
    float mr=sr/nr;
    float vr=fmaxf((qr-nr*mr*mr)/(nr-1.f), 1e-8f);
    bfl[pp-16] = log_marg(nl,ml,vl,pm,pv,nv)+log_marg(nr,mr,vr,pm,pv,nv)-lmw;
  }
  __syncthreads();
  float mv = -INFINITY;
  for (int i=t;i<TT-32;i+=256) mv = fmaxf(mv, bfl[i]);
  mv = wmaxall(mv);
  if (lane==0) rred[wid]=mv;
  __syncthreads();
  mv = fmaxf(fmaxf(rred[0],rred[1]),fmaxf(rred[2],rred[3]));
  float se=0.f, sme=0.f;
  for (int i=t;i<TT-32;i+=256){
    float e = expf(bfl[i]-mv);
    se += e;
    if (i+16 > 409) sme += e;   // pos > int(512*0.8)=409
  }
  se = wsum(se); sme = wsum(sme);
  if (lane==0){ rred[4+wid]=se; rred[8+wid]=sme; }
  __syncthreads();
  se  = (rred[4]+rred[5])+(rred[6]+rred[7]);
  sme = (rred[8]+rred[9])+(rred[10]+rred[11]);
  float near_end = (1.f/(1.f+expf(-mv))) * (sme/se);
  if (t==0) mode_ws[b] = (near_end>0.5f) ? 2 : ((extreme_prob>0.5f) ? 1 : 0);

  // ---- per-scale encodings (batched reductions: 3 barriers/scale) ----
  for (int si=0; si<SS; si++){
    int ds = 1<<si, Td = TT>>si;
    __syncthreads();
    for (int i=t;i<Td;i+=256)
      xd[i] = (si==0) ? xf[i] : (s1[(i+1)*ds]-s1[i*ds])*(1.0f/(float)ds);
    __syncthreads();
    float s=0.f, qq=0.f, mxv=-INFINITY, mnv=INFINITY;
    for (int i=t;i<Td;i+=256){ float v=xd[i]; s+=v; qq+=v*v; mxv=fmaxf(mxv,v); mnv=fminf(mnv,v); }
    s=wsum(s); qq=wsum(qq); mxv=wmaxall(mxv); mnv=wminall(mnv);
    if (lane==0){ rred[0*4+wid]=s; rred[1*4+wid]=qq; rred[2*4+wid]=mxv; rred[3*4+wid]=mnv; }
    __syncthreads();
    s   = (rred[0]+rred[1])+(rred[2]+rred[3]);
    qq  = (rred[4]+rred[5])+(rred[6]+rred[7]);
    mxv = fmaxf(fmaxf(rred[8],rred[9]),fmaxf(rred[10],rred[11]));
    mnv = fminf(fminf(rred[12],rred[13]),fminf(rred[14],rred[15]));
    float m  = s/(float)Td;
    float sd = fmaxf(sqrtf(fmaxf((qq-(float)Td*m*m)/((float)Td-1.f), 0.f)), 1e-6f);
    float tr = xd[Td-1]-xd[0];
    if (t < DD){
      float h = m*enc_W[0*DD+t] + sd*enc_W[1*DD+t] + mxv*enc_W[2*DD+t]
              + mnv*enc_W[3*DD+t] + tr*enc_W[4*DD+t] + enc_b[t];
      float mu  = wsum(h)*(1.0f/DD);
      float dv  = h-mu;
      float var = wsum(dv*dv)*(1.0f/DD);
      float hn  = dv*rsqrtf(var+1e-5f)*ln_g[t] + ln_b[t];
      float nrm2 = wsum(hn*hn);
      q_ws[(((size_t)si*BB)+b)*DD + t] = hn*rsqrtf(nrm2);
    }
  }
}

// ---------------- kernel 2: sims via split-fp16 MFMA + per-block top5 ----------------
// r7 structure + T14 async-STAGE split: key loads for tile t+1 are ISSUED to
// registers before phase A of tile t (HBM latency hides under MFMA + phase B);
// convert+ds_write happens at the top of the next iteration. 2 barriers/tile.
__global__ __launch_bounds__(256) void k2_sims(
    const float* __restrict__ keys, const int* __restrict__ labels,
    const float* __restrict__ q_ws, const int* __restrict__ mode_ws,
    float* __restrict__ cand_val, int* __restrict__ cand_idx)
{
  __shared__ __align__(16) _Float16 khi[64*KLSH];
  __shared__ __align__(16) _Float16 klo[64*KLSH];
  __shared__ float sims[64*65];    // [key][batch], stride 65 (2-way alias = free)
  int bid = blockIdx.x;
  int s   = bid / NBLK, blk = bid % NBLK;
  int t = threadIdx.x, lane = t & 63;
  int w = __builtin_amdgcn_readfirstlane(t >> 6);   // wave id, provably uniform
  int k0   = blk*KPB;
  int kend = min(MM, k0+KPB);
  int mode_l = mode_ws[lane];                        // lane = batch in phase B
  const float* kb  = keys + (size_t)s*MM*DD;
  const int*   lbb = labels + (size_t)s*MM;

  // ---- B fragments (q, split-fp16) once per block: 16 VGPR total ----
  f16x8 bh0, bl0, bh1, bl1;
  {
    int bb = w*16 + (lane&15);                 // batch (MFMA col)
    int kg = (lane>>4)*8;                      // k-group base
    const float* qg = q_ws + ((size_t)s*BB + bb)*DD + kg;
    float4 qa = *(const float4*)(qg);
    float4 qb = *(const float4*)(qg + 4);
    float4 qc = *(const float4*)(qg + 32);
    float4 qd = *(const float4*)(qg + 36);
    SPLITQ(bh0,bl0,0,qa.x) SPLITQ(bh0,bl0,1,qa.y) SPLITQ(bh0,bl0,2,qa.z) SPLITQ(bh0,bl0,3,qa.w)
    SPLITQ(bh0,bl0,4,qb.x) SPLITQ(bh0,bl0,5,qb.y) SPLITQ(bh0,bl0,6,qb.z) SPLITQ(bh0,bl0,7,qb.w)
    SPLITQ(bh1,bl1,0,qc.x) SPLITQ(bh1,bl1,1,qc.y) SPLITQ(bh1,bl1,2,qc.z) SPLITQ(bh1,bl1,3,qc.w)
    SPLITQ(bh1,bl1,4,qd.x) SPLITQ(bh1,bl1,5,qd.y) SPLITQ(bh1,bl1,6,qd.z) SPLITQ(bh1,bl1,7,qd.w)
  }

  float tv0=-INFINITY,tv1=-INFINITY,tv2=-INFINITY,tv3=-INFINITY,tv4=-INFINITY;
  int   ti0=0,ti1=0,ti2=0,ti3=0,ti4=0;

  float4 p0, p1, p2, p3;                       // in-flight staging regs
  #define ISSUE(c0n, cnn) { \
    const float* src = kb + (size_t)(c0n)*DD; \
    int lim = (cnn)*16; \
    if (t     < lim) p0 = *(const float4*)(src + (size_t)(t    )*4); \
    if (t+256 < lim) p1 = *(const float4*)(src + (size_t)(t+256)*4); \
    if (t+512 < lim) p2 = *(const float4*)(src + (size_t)(t+512)*4); \
    if (t+768 < lim) p3 = *(const float4*)(src + (size_t)(t+768)*4); }
  #define CVTW(i, v) { \
    int _key=(i)>>4, _d0=((i)&15)*4; \
    _Float16 h0=(_Float16)(v).x, h1=(_Float16)(v).y, h2=(_Float16)(v).z, h3=(_Float16)(v).w; \
    _Float16 l0=(_Float16)((v).x-(float)h0), l1=(_Float16)((v).y-(float)h1), \
             l2=(_Float16)((v).z-(float)h2), l3=(_Float16)((v).w-(float)h3); \
    *(f16x4*)&khi[_key*KLSH + _d0] = (f16x4){h0,h1,h2,h3}; \
    *(f16x4*)&klo[_key*KLSH + _d0] = (f16x4){l0,l1,l2,l3}; }
  #define SWRITE(cnn) { \
    int lim = (cnn)*16; \
    if (t     < lim) CVTW(t,     p0) \
    if (t+256 < lim) CVTW(t+256, p1) \
    if (t+512 < lim) CVTW(t+512, p2) \
    if (t+768 < lim) CVTW(t+768, p3) }

  int nt = (kend - k0 + 63) >> 6;
  ISSUE(k0, min(64, kend-k0));                 // prologue: tile 0 in flight

  for (int ti=0; ti<nt; ++ti){
    int c0 = k0 + (ti<<6);
    int cn = min(64, kend - c0);

    SWRITE(cn);                                // vmcnt-drain + convert + ds_write
    if (ti+1 < nt)
      ISSUE(c0+64, min(64, kend-c0-64));       // next tile: loads fly over phase A+B
    __syncthreads();                           // B1: planes ready

    // ---- phase A: split-fp16 MFMA (stale tail rows unread) ----
    {
      int arow = lane & 15;                    // A row within 16-key subtile
      int kg   = (lane>>4)*8;                  // A k-group
      int cc   = w*16 + (lane&15);             // D col = batch
      int drow = (lane>>4)*4;                  // D row base within subtile
      #pragma unroll
      for (int st=0; st<4; ++st){
        int rbase = (st*16 + arow)*KLSH;
        f16x8 ah0 = *(const f16x8*)&khi[rbase + kg];
        f16x8 al0 = *(const f16x8*)&klo[rbase + kg];
        f16x8 ah1 = *(const f16x8*)&khi[rbase + kg + 32];
        f16x8 al1 = *(const f16x8*)&klo[rbase + kg + 32];
        f32x4 c = {0.f, 0.f, 0.f, 0.f};
        c = __builtin_amdgcn_mfma_f32_16x16x32_f16(ah0, bh0, c, 0, 0, 0);
        c = __builtin_amdgcn_mfma_f32_16x16x32_f16(al0, bh0, c, 0, 0, 0);
        c = __builtin_amdgcn_mfma_f32_16x16x32_f16(ah0, bl0, c, 0, 0, 0);
        c = __builtin_amdgcn_mfma_f32_16x16x32_f16(ah1, bh1, c, 0, 0, 0);
        c = __builtin_amdgcn_mfma_f32_16x16x32_f16(al1, bh1, c, 0, 0, 0);
        c = __builtin_amdgcn_mfma_f32_16x16x32_f16(ah1, bl1, c, 0, 0, 0);
        int r0 = st*16 + drow;
        sims[(r0+0)*65 + cc] = c[0];
        sims[(r0+1)*65 + cc] = c[1];
        sims[(r0+2)*65 + cc] = c[2];
        sims[(r0+3)*65 + cc] = c[3];
      }
    }
    __syncthreads();                           // B2: sims ready + plane reads done

    // ---- phase B: lane = batch; each wave scans its 16-key slice ----
    {
      int mlo = w*16, mhi = min(cn, w*16+16);
      for (int m=mlo; m<mhi; m++){
        int lb = lbb[c0+m];                    // wave-uniform -> s_load
        float v = sims[m*65+lane];
        bool allowed = (mode_l==0) | (lb==mode_l);
        if (allowed){
          int gidx = c0+m;
          TOP5_INSERT(v, gidx)
        }
      }
    }
    // next iteration's SWRITE touches planes only (not sims); B1 orders sims.
  }
  #undef ISSUE
  #undef CVTW
  #undef SWRITE

  __syncthreads();
  // merge 4 wave-lists per batch -> per-block sorted top5
  float* mvp = sims;       // reuse
  int*   mip = (int*)khi;  // reuse (9216B >= 5120B)
  int slot = (w*64+lane)*5;
  mvp[slot+0]=tv0; mvp[slot+1]=tv1; mvp[slot+2]=tv2; mvp[slot+3]=tv3; mvp[slot+4]=tv4;
  mip[slot+0]=ti0; mip[slot+1]=ti1; mip[slot+2]=ti2; mip[slot+3]=ti3; mip[slot+4]=ti4;
  __syncthreads();
  if (t < 64){
    float tv0=mvp[t*5+0], tv1=mvp[t*5+1], tv2=mvp[t*5+2], tv3=mvp[t*5+3], tv4=mvp[t*5+4];
    int   ti0=mip[t*5+0], ti1=mip[t*5+1], ti2=mip[t*5+2], ti3=mip[t*5+3], ti4=mip[t*5+4];
    #pragma unroll
    for (int ww=1; ww<4; ww++){
      #pragma unroll
      for (int j=0;j<5;j++){
        float v = mvp[(ww*64+t)*5+j]; int ii = mip[(ww*64+t)*5+j];
        TOP5_INSERT(v, ii)
      }
    }
    size_t o = (((size_t)s*NBLK + blk)*BB + t)*5;
    cand_val[o+0]=tv0; cand_val[o+1]=tv1; cand_val[o+2]=tv2; cand_val[o+3]=tv3; cand_val[o+4]=tv4;
    cand_idx[o+0]=ti0; cand_idx[o+1]=ti1; cand_idx[o+2]=ti2; cand_idx[o+3]=ti3; cand_idx[o+4]=ti4;
  }
}

// ---------------- kernel 3: merge candidates, softmax, gather values ----------------
__global__ __launch_bounds__(256) void k3_merge(
    const float* __restrict__ cand_val, const int* __restrict__ cand_idx,
    const float* __restrict__ values, const float* __restrict__ thresholds,
    float* __restrict__ top1_ws, float* __restrict__ retr_ws,
    float* __restrict__ out)
{
  __shared__ float lv[NBLK*5];
  __shared__ int   li[NBLK*5];
  __shared__ float wsm[5];
  __shared__ int   wix[5];
  int bid = blockIdx.x;
  int s = bid >> 6, b = bid & 63;
  int t = threadIdx.x;
  size_t o = (((size_t)s*NBLK + t)*BB + b)*5;
  float tv0=cand_val[o+0], tv1=cand_val[o+1], tv2=cand_val[o+2], tv3=cand_val[o+3], tv4=cand_val[o+4];
  int   ti0=cand_idx[o+0], ti1=cand_idx[o+1], ti2=cand_idx[o+2], ti3=cand_idx[o+3], ti4=cand_idx[o+4];
  lv[t*5+0]=tv0; lv[t*5+1]=tv1; lv[t*5+2]=tv2; lv[t*5+3]=tv3; lv[t*5+4]=tv4;
  li[t*5+0]=ti0; li[t*5+1]=ti1; li[t*5+2]=ti2; li[t*5+3]=ti3; li[t*5+4]=ti4;
  __syncthreads();
  for (int stride=128; stride>=1; stride>>=1){
    if (t < stride){
      int p = t+stride;
      #pragma unroll
      for (int j=0;j<5;j++){
        float v = lv[p*5+j]; int ii = li[p*5+j];
        TOP5_INSERT(v, ii)
      }
      lv[t*5+0]=tv0; lv[t*5+1]=tv1; lv[t*5+2]=tv2; lv[t*5+3]=tv3; lv[t*5+4]=tv4;
      li[t*5+0]=ti0; li[t*5+1]=ti1; li[t*5+2]=ti2; li[t*5+3]=ti3; li[t*5+4]=ti4;
    }
    __syncthreads();
  }
  if (t==0){
    float e1=expf(tv1-tv0), e2=expf(tv2-tv0), e3=expf(tv3-tv0), e4=expf(tv4-tv0);
    float inv = 1.f/(1.f+e1+e2+e3+e4);
    wsm[0]=inv; wsm[1]=e1*inv; wsm[2]=e2*inv; wsm[3]=e3*inv; wsm[4]=e4*inv;
    wix[0]=ti0; wix[1]=ti1; wix[2]=ti2; wix[3]=ti3; wix[4]=ti4;
    top1_ws[s*BB+b] = tv0;
    out[(size_t)BB*PRED*NCH + b*SS + s] = 1.f/(1.f+expf(-(tv0-thresholds[s])));
  }
  __syncthreads();
  if (t < PRED){
    float acc=0.f;
    #pragma unroll
    for (int j=0;j<5;j++)
      acc += wsm[j]*values[((size_t)s*MM + wix[j])*PRED + t];
    retr_ws[((size_t)s*BB + b)*PRED + t] = acc;
  }
}

// ---------------- kernel 4: cross-scale fuse + broadcast over channels ----------------
__global__ __launch_bounds__(128) void k4_fuse(
    const float* __restrict__ top1_ws, const float* __restrict__ retr_ws,
    float* __restrict__ out)
{
  int b = blockIdx.x, t = threadIdx.x;
  float t0=top1_ws[b], t1=top1_ws[BB+b], t2=top1_ws[2*BB+b], t3=top1_ws[3*BB+b];
  float mx = fmaxf(fmaxf(t0,t1),fmaxf(t2,t3));
  float e0=expf(t0-mx), e1=expf(t1-mx), e2=expf(t2-mx), e3=expf(t3-mx);
  float inv = 1.f/(e0+e1+e2+e3);
  if (t < PRED){
    float f = (e0*retr_ws[((size_t)0*BB+b)*PRED+t] + e1*retr_ws[((size_t)1*BB+b)*PRED+t]
             + e2*retr_ws[((size_t)2*BB+b)*PRED+t] + e3*retr_ws[((size_t)3*BB+b)*PRED+t]) * inv;
    size_t base = ((size_t)b*PRED + t)*NCH;
    #pragma unroll
    for (int n=0;n<NCH;n++) out[base+n] = f;
  }
}

extern "C" void kernel_launch(void* const* d_in, const int* in_sizes, int n_in,
                              void* d_out, int out_size, void* d_ws, size_t ws_size,
                              hipStream_t stream)
{
  const float* x          = (const float*)d_in[0];
  const float* keys       = (const float*)d_in[1];
  const float* values     = (const float*)d_in[2];
  const int*   labels     = (const int*)  d_in[3];
  const float* thresholds = (const float*)d_in[4];
  const float* cls_w      = (const float*)d_in[5];
  const float* cls_b      = (const float*)d_in[6];
  const float* prior_mean = (const float*)d_in[7];
  const float* prior_var  = (const float*)d_in[8];
  const float* noise_var  = (const float*)d_in[9];
  const float* enc_W      = (const float*)d_in[10];
  const float* enc_b      = (const float*)d_in[11];
  const float* ln_g       = (const float*)d_in[12];
  const float* ln_b       = (const float*)d_in[13];
  float* out = (float*)d_out;

  float* q_ws     = (float*)d_ws;                                   // S*B*D
  int*   mode_ws  = (int*)(q_ws + (size_t)SS*BB*DD);                // B
  float* cand_val = (float*)(mode_ws + BB);                         // S*NBLK*B*5
  int*   cand_idx = (int*)(cand_val + (size_t)SS*NBLK*BB*5);        // S*NBLK*B*5
  float* top1_ws  = (float*)(cand_idx + (size_t)SS*NBLK*BB*5);      // S*B
  float* retr_ws  = top1_ws + SS*BB;                                // S*B*PRED

  k1_setup<<<dim3(BB), dim3(256), 0, stream>>>(x, cls_w, cls_b, prior_mean,
      prior_var, noise_var, enc_W, enc_b, ln_g, ln_b, q_ws, mode_ws);
  k2_sims<<<dim3(SS*NBLK), dim3(256), 0, stream>>>(keys, labels, q_ws, mode_ws,
      cand_val, cand_idx);
  k3_merge<<<dim3(SS*BB), dim3(256), 0, stream>>>(cand_val, cand_idx, values,
      thresholds, top1_ws, retr_ws, out);
  k4_fuse<<<dim3(BB), dim3(128), 0, stream>>>(top1_ws, retr_ws, out);
}